// Round 4
// baseline (747.169 us; speedup 1.0000x reference)
//
#include <hip/hip_runtime.h>

// Problem constants: B=32, T=128, NQ=1000, NC=64, DK=128, DA=128
#define B_  32
#define T_  128
#define HFS 132   // h fp32 staging row stride (floats); rows 528B (16B-aligned)
#define HBS 136   // h bf16 LDS row stride (ushorts); rows 272B (16B-aligned)

typedef __attribute__((ext_vector_type(8))) short bf16x8;
typedef __attribute__((ext_vector_type(4))) float f32x4;

__device__ __forceinline__ float sigf(float x){ return __builtin_amdgcn_rcpf(1.f + __expf(-x)); }
__device__ __forceinline__ float tanh_f(float x){ return 2.f*__builtin_amdgcn_rcpf(1.f + __expf(-2.f*x)) - 1.f; }
__device__ __forceinline__ unsigned short f2b(float x){
  union { float f; unsigned int u; } v; v.f = x;
  return (unsigned short)((v.u + 0x7FFFu + ((v.u >> 16) & 1u)) >> 16);  // RNE bf16
}
// LDS-only barrier: skip the vmcnt(0) drain __syncthreads() emits.
__device__ __forceinline__ void bar_lds(){
  __builtin_amdgcn_sched_barrier(0);
  asm volatile("s_waitcnt lgkmcnt(0)" ::: "memory");
  __builtin_amdgcn_s_barrier();
  __builtin_amdgcn_sched_barrier(0);
}

// ---------------- stage: bf16 weight copies + a-part rowsum of W1 ----------------
__global__ __launch_bounds__(256) void stage_k(
    const float* __restrict__ W2, const float* __restrict__ W3,
    const float* __restrict__ W4, const float* __restrict__ W1,
    unsigned short* __restrict__ W2b, unsigned short* __restrict__ W3b,
    unsigned short* __restrict__ W4b, float* __restrict__ S)
{
  int i = blockIdx.x*256 + threadIdx.x;
  if (i < 128*384){ W2b[i] = f2b(W2[i]); W3b[i] = f2b(W3[i]); }
  if (i < 128*256){ W4b[i] = f2b(W4[i]); }
  if (i < 128){
    float s = 0.f;
    const float* row = W1 + (size_t)i*256 + 128;
    for (int k = 0; k < 128; ++k) s += row[k];
    S[i] = s;   // sum_k W1[i][128+k]  (a_rep constant along DA)
  }
}

// ---------------- prep: q_emb gather, qa GEMM (fp32 exact), pred[:,0]=0 ----------
__global__ __launch_bounds__(256) void prep_k(
    const int* __restrict__ qd, const float* __restrict__ ad,
    const float* __restrict__ qew, const float* __restrict__ W1,
    const float* __restrict__ b1, const float* __restrict__ S,
    float* __restrict__ oqe, float* __restrict__ oqa, float* __restrict__ pred)
{
  __shared__ float qe[16][128];
  __shared__ float w1c[128][65];
  const int tid = threadIdx.x;
  const int bt0 = blockIdx.x * 16;

  for (int i = tid; i < 16*128; i += 256){
    int r = i >> 7, d = i & 127;
    float v = qew[(size_t)qd[bt0 + r]*128 + d];
    qe[r][d] = v;
    oqe[(size_t)(bt0 + r)*128 + d] = v;
  }
  const int j = tid & 127, rh = tid >> 7;
  float accv[8];
  {
    float base = b1[j], Sj = S[j];
#pragma unroll
    for (int r = 0; r < 8; ++r) accv[r] = fmaf(ad[bt0 + rh*8 + r], Sj, base);
  }
  for (int c = 0; c < 2; ++c){
    __syncthreads();
    for (int i = tid; i < 128*64; i += 256){
      int jj = i >> 6, kk = i & 63;
      w1c[jj][kk] = W1[(size_t)jj*256 + c*64 + kk];
    }
    __syncthreads();
#pragma unroll 4
    for (int k = 0; k < 64; ++k){
      float wv = w1c[j][k];
#pragma unroll
      for (int r = 0; r < 8; ++r) accv[r] = fmaf(qe[rh*8 + r][c*64 + k], wv, accv[r]);
    }
  }
#pragma unroll
  for (int r = 0; r < 8; ++r) oqa[(size_t)(bt0 + rh*8 + r)*128 + j] = accv[r];
  if (blockIdx.x == 0 && tid < 32) pred[tid * T_] = 0.f;
}

// ---------------- recur: 127-step recurrence, one block per batch -----------------
// Wave map (GEMM): mg = w&1 (M-group of 32 rows), nq = w>>1 (N-group of 32 cols).
// Thread owns h(n,j) for n=(mg*2+mi)*16+g*4+r, j=(nq*2+ni)*16+li -> fp32 h in REGISTERS.
struct __align__(16) Sm {
  float hfs[64*HFS];            // fp32 h staging for coalesced H writes (33.8 KB)
  unsigned short hb[2][64*HBS]; // bf16 h, double-buffered (MFMA A operand) (34.8 KB)
  float qe[3][64];              // qm rows, triple-buffered
  float kcf[128];
  float htp[2*128];             // h_tilde partials per M-group
  unsigned short kcb[128];
  unsigned short cat3[384];     // [learning_pre | learning | h_tilde_pre] bf16
  int qdl[T_];
};

__global__ __launch_bounds__(512) void recur_k(
    const int* __restrict__ qd, const float* __restrict__ qmx,
    const float* __restrict__ h0,
    const float* __restrict__ b2, const float* __restrict__ b3,
    const float* __restrict__ b4,
    const unsigned short* __restrict__ W2b, const unsigned short* __restrict__ W3b,
    const unsigned short* __restrict__ W4b,
    const float* __restrict__ oqa,
    float* __restrict__ H, unsigned short* __restrict__ HTg)
{
  __shared__ Sm s;
  const int b   = blockIdx.x;
  const int tid = threadIdx.x;
  const int w = tid >> 6, lane = tid & 63, g = lane >> 4, li = lane & 15;
  const int mg = w & 1, nq = w >> 1;

  // ---- register-resident weights
  bf16x8 w2f[12], w3f[12];                 // GEMV rows j = w*16+li
#pragma unroll
  for (int ks = 0; ks < 12; ++ks){
    w2f[ks] = *(const bf16x8*)(W2b + (size_t)(w*16 + li)*384 + ks*32 + 8*g);
    w3f[ks] = *(const bf16x8*)(W3b + (size_t)(w*16 + li)*384 + ks*32 + 8*g);
  }
  bf16x8 w4f[2][8];                        // GEMM B rows j = (nq*2+ni)*16+li
#pragma unroll
  for (int ni = 0; ni < 2; ++ni)
#pragma unroll
    for (int ks = 0; ks < 8; ++ks)
      w4f[ni][ks] = *(const bf16x8*)(W4b + (size_t)((nq*2+ni)*16 + li)*256 + ks*32 + 8*g);

  const float b2v = b2[w*16 + li], b3v = b3[w*16 + li];
  float b4v[2];
#pragma unroll
  for (int ni = 0; ni < 2; ++ni) b4v[ni] = b4[(nq*2+ni)*16 + li];

  // ---- fp32 h state in registers
  float hreg[2][2][4];
#pragma unroll
  for (int mi = 0; mi < 2; ++mi)
#pragma unroll
    for (int ni = 0; ni < 2; ++ni)
#pragma unroll
      for (int r = 0; r < 4; ++r){
        int n = (mg*2 + mi)*16 + g*4 + r, j = (nq*2 + ni)*16 + li;
        hreg[mi][ni][r] = h0[n*128 + j];
      }

  // ---- init: hb[0]; H[0] = sigmoid(h0); qd row; qe rows 0,1
  for (int i = tid; i < 64*128; i += 512){
    int n = i >> 7, d = i & 127;
    float v = h0[i];
    s.hb[0][n*HBS + d] = f2b(v);
    H[(size_t)b*8192 + i] = sigf(v);
  }
  if (tid < T_) s.qdl[tid] = qd[b*T_ + tid];
  __syncthreads();
  if (tid < 64){
    s.qe[0][tid] = qmx[(size_t)s.qdl[0]*64 + tid];
    s.qe[1][tid] = qmx[(size_t)s.qdl[1]*64 + tid];
  }
  __syncthreads();
  if (tid < 128){   // h_tilde0 + initial cat3 (learning_pre=0, learning=qa[:,0])
    float acc = 0.f;
    for (int n = 0; n < 64; ++n) acc = fmaf(s.qe[0][n], h0[n*128 + tid], acc);
    s.cat3[tid]       = 0;
    s.cat3[128 + tid] = f2b(oqa[(size_t)b*T_*128 + tid]);
    s.cat3[256 + tid] = f2b(acc);
  }
  __syncthreads();

#pragma unroll 1
  for (int t = 0; t < T_-1; ++t){
    const int cur = t & 1, nxt = cur ^ 1;
    // prefetches (consumed in phase D)
    float qav = 0.f, qmxv = 0.f;
    if (tid < 128) qav = oqa[((size_t)b*T_ + t+1)*128 + tid];
    if (tid >= 256 && tid < 320 && t+2 < T_)
      qmxv = qmx[(size_t)s.qdl[t+2]*64 + (tid-256)];

    // ---- A: KP/R GEMVs from register weights; fold KC
    {
      bf16x8 av[12];
#pragma unroll
      for (int ks = 0; ks < 12; ++ks) av[ks] = *(const bf16x8*)&s.cat3[ks*32 + 8*g];
      f32x4 a2[3] = {{0,0,0,0},{0,0,0,0},{0,0,0,0}};
      f32x4 a3[3] = {{0,0,0,0},{0,0,0,0},{0,0,0,0}};
#pragma unroll
      for (int ks = 0; ks < 4; ++ks){
        a2[0] = __builtin_amdgcn_mfma_f32_16x16x32_bf16(av[ks],   w2f[ks],   a2[0], 0,0,0);
        a3[0] = __builtin_amdgcn_mfma_f32_16x16x32_bf16(av[ks],   w3f[ks],   a3[0], 0,0,0);
        a2[1] = __builtin_amdgcn_mfma_f32_16x16x32_bf16(av[ks+4], w2f[ks+4], a2[1], 0,0,0);
        a3[1] = __builtin_amdgcn_mfma_f32_16x16x32_bf16(av[ks+4], w3f[ks+4], a3[1], 0,0,0);
        a2[2] = __builtin_amdgcn_mfma_f32_16x16x32_bf16(av[ks+8], w2f[ks+8], a2[2], 0,0,0);
        a3[2] = __builtin_amdgcn_mfma_f32_16x16x32_bf16(av[ks+8], w3f[ks+8], a3[2], 0,0,0);
      }
      if (g == 0){
        int jj = w*16 + li;
        float kp = tanh_f(a2[0][0] + a2[1][0] + a2[2][0] + b2v);
        float rr = sigf (a3[0][0] + a3[1][0] + a3[2][0] + b3v);
        float kc = rr*(kp + 1.f)*0.5f;
        s.kcf[jj] = kc; s.kcb[jj] = f2b(kc);
      }
    }
    bar_lds();                             // B1: kcb/kcf ready

    // ---- C': z = [h|KC]@W4^T ; h = qe*KC + sig(z)*h ; staging writes ; ht partials
    {
      bf16x8 af[2][4], kf[4];
#pragma unroll
      for (int mi = 0; mi < 2; ++mi)
#pragma unroll
        for (int ks = 0; ks < 4; ++ks)
          af[mi][ks] = *(const bf16x8*)&s.hb[cur][((mg*2+mi)*16 + li)*HBS + ks*32 + 8*g];
#pragma unroll
      for (int ks = 0; ks < 4; ++ks) kf[ks] = *(const bf16x8*)&s.kcb[ks*32 + 8*g];
      float qc[2][4], qn[2][4];
#pragma unroll
      for (int mi = 0; mi < 2; ++mi)
#pragma unroll
        for (int r = 0; r < 4; ++r){
          int n = (mg*2 + mi)*16 + g*4 + r;
          qc[mi][r] = s.qe[t%3][n];
          qn[mi][r] = s.qe[(t+1)%3][n];
        }
      f32x4 acc[2][2] = {{{0,0,0,0},{0,0,0,0}},{{0,0,0,0},{0,0,0,0}}};
#pragma unroll
      for (int ks = 0; ks < 4; ++ks){
        acc[0][0] = __builtin_amdgcn_mfma_f32_16x16x32_bf16(af[0][ks], w4f[0][ks], acc[0][0], 0,0,0);
        acc[0][1] = __builtin_amdgcn_mfma_f32_16x16x32_bf16(af[0][ks], w4f[1][ks], acc[0][1], 0,0,0);
        acc[1][0] = __builtin_amdgcn_mfma_f32_16x16x32_bf16(af[1][ks], w4f[0][ks], acc[1][0], 0,0,0);
        acc[1][1] = __builtin_amdgcn_mfma_f32_16x16x32_bf16(af[1][ks], w4f[1][ks], acc[1][1], 0,0,0);
      }
#pragma unroll
      for (int ks = 0; ks < 4; ++ks){
        acc[0][0] = __builtin_amdgcn_mfma_f32_16x16x32_bf16(kf[ks], w4f[0][ks+4], acc[0][0], 0,0,0);
        acc[0][1] = __builtin_amdgcn_mfma_f32_16x16x32_bf16(kf[ks], w4f[1][ks+4], acc[0][1], 0,0,0);
        acc[1][0] = __builtin_amdgcn_mfma_f32_16x16x32_bf16(kf[ks], w4f[0][ks+4], acc[1][0], 0,0,0);
        acc[1][1] = __builtin_amdgcn_mfma_f32_16x16x32_bf16(kf[ks], w4f[1][ks+4], acc[1][1], 0,0,0);
      }
      float kcj[2];
#pragma unroll
      for (int ni = 0; ni < 2; ++ni) kcj[ni] = s.kcf[(nq*2+ni)*16 + li];
#pragma unroll
      for (int ni = 0; ni < 2; ++ni){
        int j = (nq*2 + ni)*16 + li;
        float part = 0.f;
#pragma unroll
        for (int mi = 0; mi < 2; ++mi){
#pragma unroll
          for (int r = 0; r < 4; ++r){
            int n = (mg*2 + mi)*16 + g*4 + r;   // C/D: row=(lane>>4)*4+r, col=lane&15
            float sg = sigf(acc[mi][ni][r] + b4v[ni]);
            float hn = fmaf(qc[mi][r], kcj[ni], sg*hreg[mi][ni][r]);
            hreg[mi][ni][r] = hn;
            s.hfs[n*HFS + j]      = hn;
            s.hb[nxt][n*HBS + j]  = f2b(hn);
            part = fmaf(qn[mi][r], hn, part);
          }
        }
        part += __shfl_xor(part, 16);
        part += __shfl_xor(part, 32);
        if (g == 0) s.htp[mg*128 + j] = part;
      }
    }
    bar_lds();                             // B4: hfs/hb[nxt]/htp ready

    // ---- D: ht reduce + cat3 shift + HTg + coalesced H copy + qe prefetch write
    if (tid < 128){
      float ht = s.htp[tid] + s.htp[128 + tid];
      unsigned short curl = s.cat3[128 + tid];
      s.cat3[tid]       = curl;
      s.cat3[128 + tid] = f2b(qav);
      s.cat3[256 + tid] = f2b(ht);
      HTg[((size_t)b*T_ + t + 1)*128 + tid] = f2b(ht);
    } else if (tid >= 256 && tid < 320){
      if (t+2 < T_) s.qe[(t+2)%3][tid-256] = qmxv;
    }
    if (t < T_-2){
      float* Ho = H + ((size_t)(t+1)*B_ + b)*8192;
#pragma unroll
      for (int k = 0; k < 4; ++k){
        int f = tid + k*512;                 // float4 index in [0,2048)
        int n = f >> 5, d = (f & 31)*4;
        f32x4 v = *(const f32x4*)&s.hfs[n*HFS + d];
        *(f32x4*)&Ho[n*128 + d] = v;         // raw h; sig_k applies sigmoid later
      }
    }
    bar_lds();                             // B5: cat3/qe ready for next step
  }
}

// ---------------- sig_k: in-place sigmoid of H[1..126] ---------------------------
__global__ __launch_bounds__(256) void sig_k(float* __restrict__ H)
{
  const size_t n4 = (size_t)126*32*2048;   // float4 count
  f32x4* p = (f32x4*)(H + (size_t)32*8192);
  for (size_t i = (size_t)blockIdx.x*256 + threadIdx.x; i < n4; i += (size_t)gridDim.x*256){
    f32x4 v = p[i];
    v[0] = sigf(v[0]); v[1] = sigf(v[1]); v[2] = sigf(v[2]); v[3] = sigf(v[3]);
    p[i] = v;
  }
}

// ---------------- ypost: deferred y GEMV over all (b, tau>=1) --------------------
__global__ __launch_bounds__(256) void ypost_k(
    const float* __restrict__ oqe, const unsigned short* __restrict__ HT,
    const float* __restrict__ W5, const float* __restrict__ b5,
    float* __restrict__ pred)
{
  __shared__ float X[32][256];
  __shared__ float w5c[128][33];
  const int tau = blockIdx.x + 1;
  const int tid = threadIdx.x;

  for (int i = tid; i < 32*128; i += 256){
    int bb = i >> 7, k = i & 127;
    X[bb][k] = oqe[((size_t)bb*T_ + tau)*128 + k];
    union { unsigned int u; float f; } cv;
    cv.u = ((unsigned int)HT[((size_t)bb*T_ + tau)*128 + k]) << 16;
    X[bb][128 + k] = cv.f;
  }
  const int j = tid & 127, rh = tid >> 7;
  float acc[16];
  float base = b5[j];
#pragma unroll
  for (int r = 0; r < 16; ++r) acc[r] = base;
  for (int c = 0; c < 8; ++c){
    __syncthreads();
    for (int i = tid; i < 128*32; i += 256){
      int jj = i >> 5, kk = i & 31;
      w5c[jj][kk] = W5[(size_t)jj*256 + c*32 + kk];
    }
    __syncthreads();
#pragma unroll 8
    for (int k = 0; k < 32; ++k){
      float wv = w5c[j][k];
#pragma unroll
      for (int r = 0; r < 16; ++r) acc[r] = fmaf(X[rh*16 + r][c*32 + k], wv, acc[r]);
    }
  }
  __syncthreads();
#pragma unroll
  for (int r = 0; r < 16; ++r) X[rh*16 + r][j] = sigf(acc[r]);
  __syncthreads();
  if (tid < 32){
    float ssum = 0.f;
    for (int k = 0; k < 128; ++k) ssum += X[tid][k];
    pred[tid*T_ + tau] = ssum * (1.f/128.f);
  }
}

extern "C" void kernel_launch(void* const* d_in, const int* in_sizes, int n_in,
                              void* d_out, int out_size, void* d_ws, size_t ws_size,
                              hipStream_t stream)
{
  const int*   qd  = (const int*)  d_in[0];
  const float* ad  = (const float*)d_in[1];
  const float* qmx = (const float*)d_in[2];
  const float* qew = (const float*)d_in[3];
  const float* W1  = (const float*)d_in[4];
  const float* b1  = (const float*)d_in[5];
  const float* W2  = (const float*)d_in[6];
  const float* b2  = (const float*)d_in[7];
  const float* W3  = (const float*)d_in[8];
  const float* b3  = (const float*)d_in[9];
  const float* W4  = (const float*)d_in[10];
  const float* b4  = (const float*)d_in[11];
  const float* W5  = (const float*)d_in[12];
  const float* b5  = (const float*)d_in[13];
  const float* h0  = (const float*)d_in[14];

  float* H    = (float*)d_out;                         // [127][32][64][128]
  float* pred = H    + (size_t)127*32*64*128;          // [32][128]
  float* oqe  = pred + (size_t)32*128;                 // [32][128][128]
  float* oqa  = oqe  + (size_t)32*128*128;             // [32][128][128]

  unsigned short* W2b = (unsigned short*)d_ws;         // [128][384] bf16
  unsigned short* W3b = W2b + 128*384;
  unsigned short* W4b = W3b + 128*384;                 // [128][256] bf16
  float*          S   = (float*)(W4b + 128*256);       // [128]
  unsigned short* HTg = (unsigned short*)(S + 128);    // [32][128][128] bf16 h_tilde

  stage_k<<<192, 256, 0, stream>>>(W2, W3, W4, W1, W2b, W3b, W4b, S);
  prep_k <<<256, 256, 0, stream>>>(qd, ad, qew, W1, b1, S, oqe, oqa, pred);
  recur_k<<<32,  512, 0, stream>>>(qd, qmx, h0, b2, b3, b4,
                                   W2b, W3b, W4b, oqa, H, HTg);
  sig_k  <<<2048, 256, 0, stream>>>(H);
  ypost_k<<<127, 256, 0, stream>>>(oqe, HTg, W5, b5, pred);
}

// Round 5
// 408.205 us; speedup vs baseline: 1.8304x; 1.8304x over previous
//
#include <hip/hip_runtime.h>

// Problem constants: B=32, T=128, NQ=1000, NC=64, DK=128, DA=128
#define B_  32
#define T_  128
#define HFS 132   // h fp32 staging row stride (floats); rows 528B
#define HBS 136   // h bf16 LDS row stride (ushorts); rows 272B, 68 dwords -> +4 bank stagger

typedef __attribute__((ext_vector_type(8))) short bf16x8;
typedef __attribute__((ext_vector_type(4))) float f32x4;

__device__ __forceinline__ float sigf(float x){ return __builtin_amdgcn_rcpf(1.f + __expf(-x)); }
__device__ __forceinline__ float tanh_f(float x){ return 2.f*__builtin_amdgcn_rcpf(1.f + __expf(-2.f*x)) - 1.f; }
__device__ __forceinline__ unsigned short f2b(float x){
  union { float f; unsigned int u; } v; v.f = x;
  return (unsigned short)((v.u + 0x7FFFu + ((v.u >> 16) & 1u)) >> 16);  // RNE bf16
}
__device__ __forceinline__ float b2f(unsigned short u){
  union { unsigned int x; float f; } v; v.x = ((unsigned int)u) << 16; return v.f;
}
// LDS-only barrier: skip the vmcnt(0) drain __syncthreads() emits.
__device__ __forceinline__ void bar_lds(){
  __builtin_amdgcn_sched_barrier(0);
  asm volatile("s_waitcnt lgkmcnt(0)" ::: "memory");
  __builtin_amdgcn_s_barrier();
  __builtin_amdgcn_sched_barrier(0);
}

// ---------------- stage: bf16 weight copies + a-part rowsum of W1 ----------------
__global__ __launch_bounds__(256) void stage_k(
    const float* __restrict__ W2, const float* __restrict__ W3,
    const float* __restrict__ W4, const float* __restrict__ W1,
    unsigned short* __restrict__ W2b, unsigned short* __restrict__ W3b,
    unsigned short* __restrict__ W4b, float* __restrict__ S)
{
  int i = blockIdx.x*256 + threadIdx.x;
  if (i < 128*384){ W2b[i] = f2b(W2[i]); W3b[i] = f2b(W3[i]); }
  if (i < 128*256){ W4b[i] = f2b(W4[i]); }
  if (i < 128){
    float s = 0.f;
    const float* row = W1 + (size_t)i*256 + 128;
    for (int k = 0; k < 128; ++k) s += row[k];
    S[i] = s;   // sum_k W1[i][128+k]  (a_rep constant along DA)
  }
}

// ---------------- prep: q_emb gather, qa GEMM (fp32 exact), pred[:,0]=0 ----------
__global__ __launch_bounds__(256) void prep_k(
    const int* __restrict__ qd, const float* __restrict__ ad,
    const float* __restrict__ qew, const float* __restrict__ W1,
    const float* __restrict__ b1, const float* __restrict__ S,
    float* __restrict__ oqe, float* __restrict__ oqa, float* __restrict__ pred)
{
  __shared__ float qe[16][128];
  __shared__ float w1c[128][65];
  const int tid = threadIdx.x;
  const int bt0 = blockIdx.x * 16;

  for (int i = tid; i < 16*128; i += 256){
    int r = i >> 7, d = i & 127;
    float v = qew[(size_t)qd[bt0 + r]*128 + d];
    qe[r][d] = v;
    oqe[(size_t)(bt0 + r)*128 + d] = v;
  }
  const int j = tid & 127, rh = tid >> 7;
  float accv[8];
  {
    float base = b1[j], Sj = S[j];
#pragma unroll
    for (int r = 0; r < 8; ++r) accv[r] = fmaf(ad[bt0 + rh*8 + r], Sj, base);
  }
  for (int c = 0; c < 2; ++c){
    __syncthreads();
    for (int i = tid; i < 128*64; i += 256){
      int jj = i >> 6, kk = i & 63;
      w1c[jj][kk] = W1[(size_t)jj*256 + c*64 + kk];
    }
    __syncthreads();
#pragma unroll 4
    for (int k = 0; k < 64; ++k){
      float wv = w1c[j][k];
#pragma unroll
      for (int r = 0; r < 8; ++r) accv[r] = fmaf(qe[rh*8 + r][c*64 + k], wv, accv[r]);
    }
  }
#pragma unroll
  for (int r = 0; r < 8; ++r) oqa[(size_t)(bt0 + rh*8 + r)*128 + j] = accv[r];
  if (blockIdx.x == 0 && tid < 32) pred[tid * T_] = 0.f;
}

// ---------------- l23: precompute learning part of W2/W3 GEMVs -------------------
// L2c[b,t,j] = b2[j] + sum_{k<128} W2[j,k]*qa[b,t-1,k] + W2[j,128+k]*qa[b,t,k]
// = rows t of (A2 @ W2[:, :256]^T) with A2[t] = [qa[t-1] | qa[t]] (qa[-1]=0).
// One block per b; M=128 (t, row 127 dropped), N=128 (j), K=256. bf16 MFMA.
__global__ __launch_bounds__(512) void l23_k(
    const float* __restrict__ oqa,
    const unsigned short* __restrict__ W2b, const unsigned short* __restrict__ W3b,
    const float* __restrict__ b2, const float* __restrict__ b3,
    unsigned short* __restrict__ L2b, unsigned short* __restrict__ L3b)
{
  __shared__ unsigned short qab[129*136];   // row r = qa[b, r-1]; row 0 = zeros
  const int b = blockIdx.x, tid = threadIdx.x;
  const int w = tid >> 6, lane = tid & 63, g = lane >> 4, li = lane & 15;
  const int mw = w & 3, nw = w >> 2;        // wave: m-tiles {2mw,2mw+1}, n-tiles {4nw..4nw+3}

  for (int i = tid; i < 129*128; i += 512){
    int row = i >> 7, k = i & 127;
    qab[row*136 + k] = row ? f2b(oqa[((size_t)b*T_ + row-1)*128 + k]) : (unsigned short)0;
  }
  __syncthreads();

  const unsigned short* Wp[2] = {W2b, W3b};
  const float*          bp[2] = {b2, b3};
  unsigned short*       Lp[2] = {L2b, L3b};
#pragma unroll
  for (int m_ = 0; m_ < 2; ++m_){
    bf16x8 bfr[4][8];
#pragma unroll
    for (int nt4 = 0; nt4 < 4; ++nt4){
      int j = (nw*4 + nt4)*16 + li;
#pragma unroll
      for (int ks = 0; ks < 8; ++ks)
        bfr[nt4][ks] = *(const bf16x8*)(Wp[m_] + (size_t)j*384 + ks*32 + 8*g);
    }
    f32x4 acc[2][4] = {{{0,0,0,0},{0,0,0,0},{0,0,0,0},{0,0,0,0}},
                       {{0,0,0,0},{0,0,0,0},{0,0,0,0},{0,0,0,0}}};
#pragma unroll
    for (int mt2 = 0; mt2 < 2; ++mt2){
      int row = (mw*2 + mt2)*16 + li;       // output t-row
      bf16x8 afr[8];
#pragma unroll
      for (int ks = 0; ks < 4; ++ks){
        afr[ks]   = *(const bf16x8*)&qab[ row   *136 + ks*32 + 8*g];  // qa[t-1]
        afr[ks+4] = *(const bf16x8*)&qab[(row+1)*136 + ks*32 + 8*g];  // qa[t]
      }
#pragma unroll
      for (int ks = 0; ks < 8; ++ks)
#pragma unroll
        for (int nt4 = 0; nt4 < 4; ++nt4)
          acc[mt2][nt4] = __builtin_amdgcn_mfma_f32_16x16x32_bf16(afr[ks], bfr[nt4][ks], acc[mt2][nt4], 0,0,0);
    }
    float bias[4];
#pragma unroll
    for (int nt4 = 0; nt4 < 4; ++nt4) bias[nt4] = bp[m_][(nw*4 + nt4)*16 + li];
#pragma unroll
    for (int mt2 = 0; mt2 < 2; ++mt2)
#pragma unroll
      for (int nt4 = 0; nt4 < 4; ++nt4)
#pragma unroll
        for (int r = 0; r < 4; ++r){
          int t = (mw*2 + mt2)*16 + g*4 + r;   // C/D: row=(lane>>4)*4+r, col=lane&15
          int j = (nw*4 + nt4)*16 + li;
          if (t < 127) Lp[m_][((size_t)b*127 + t)*128 + j] = f2b(acc[mt2][nt4][r] + bias[nt4]);
        }
  }
}

// ---------------- recur: 127-step recurrence, one block per batch -----------------
// Wave w owns output cols j = w*16+li (all 64 rows). Thread owns h(n,j) for
// n = mt*16 + g*4 + r (mt<4). kc for col j computed in-lane (no LDS round trip).
struct __align__(16) SmR {
  float hfs[64*HFS];            // fp32 h staging for coalesced H writes
  unsigned short hb[2][64*HBS]; // bf16 h, double-buffered (MFMA A operand)
  float qe[3][64];              // qm rows, triple-buffered
  unsigned short htb[128];      // h_tilde bf16 (GEMV A operand, broadcast)
  unsigned short kcb[128];      // KC bf16 (GEMM A operand, broadcast)
  int qdl[T_];
};

__global__ __launch_bounds__(512) void recur_k(
    const int* __restrict__ qd, const float* __restrict__ qmx,
    const float* __restrict__ h0, const float* __restrict__ b4,
    const unsigned short* __restrict__ W2b, const unsigned short* __restrict__ W3b,
    const unsigned short* __restrict__ W4b,
    const unsigned short* __restrict__ L2b, const unsigned short* __restrict__ L3b,
    float* __restrict__ H, unsigned short* __restrict__ HTg)
{
  __shared__ SmR s;
  const int b   = blockIdx.x;
  const int tid = threadIdx.x;
  const int w = tid >> 6, lane = tid & 63, g = lane >> 4, li = lane & 15;
  const int j = w*16 + li;

  // ---- register-resident weights
  bf16x8 w2cf[4], w3cf[4];      // W2/W3[:, 256:384] rows j (h_tilde slice)
#pragma unroll
  for (int ks = 0; ks < 4; ++ks){
    w2cf[ks] = *(const bf16x8*)(W2b + (size_t)j*384 + 256 + ks*32 + 8*g);
    w3cf[ks] = *(const bf16x8*)(W3b + (size_t)j*384 + 256 + ks*32 + 8*g);
  }
  bf16x8 w4f[8];                // W4 rows j, K=256
#pragma unroll
  for (int ks = 0; ks < 8; ++ks)
    w4f[ks] = *(const bf16x8*)(W4b + (size_t)j*256 + ks*32 + 8*g);
  const float b4v = b4[j];

  // ---- fp32 h state in registers: hreg[mt][r] = h(mt*16+g*4+r, j)
  float hreg[4][4];
#pragma unroll
  for (int mt = 0; mt < 4; ++mt)
#pragma unroll
    for (int r = 0; r < 4; ++r)
      hreg[mt][r] = h0[(mt*16 + g*4 + r)*128 + j];

  // ---- init
  for (int i = tid; i < 64*128; i += 512){
    int n = i >> 7, d = i & 127;
    float v = h0[i];
    s.hb[0][n*HBS + d] = f2b(v);
    H[(size_t)b*8192 + i] = sigf(v);
  }
  if (tid < T_) s.qdl[tid] = qd[b*T_ + tid];
  __syncthreads();
  if (tid < 64){
    s.qe[0][tid] = qmx[(size_t)s.qdl[0]*64 + tid];
    s.qe[1][tid] = qmx[(size_t)s.qdl[1]*64 + tid];
  }
  __syncthreads();
  if (tid < 128){   // h_tilde0
    float acc = 0.f;
    for (int n = 0; n < 64; ++n) acc = fmaf(s.qe[0][n], h0[n*128 + tid], acc);
    s.htb[tid] = f2b(acc);
  }
  __syncthreads();

  float l2v = b2f(L2b[((size_t)b*127)*128 + j]);
  float l3v = b2f(L3b[((size_t)b*127)*128 + j]);

#pragma unroll 1
  for (int t = 0; t < T_-1; ++t){
    const int cur = t & 1, nxt = cur ^ 1;

    // ---- AB phase ----
    // prefetches (consumed next phase / next step)
    int tp1 = (t+1 < 127) ? t+1 : 126;
    unsigned short l2n = L2b[((size_t)b*127 + tp1)*128 + j];
    unsigned short l3n = L3b[((size_t)b*127 + tp1)*128 + j];
    float qmxv = 0.f;
    if (tid < 64 && t+2 < T_) qmxv = qmx[(size_t)s.qdl[t+2]*64 + tid];

    // GEMV (critical path): o2/o3 = W2c/W3c @ h_tilde  (K=128, 2-deep chains)
    bf16x8 av[4];
#pragma unroll
    for (int ks = 0; ks < 4; ++ks) av[ks] = *(const bf16x8*)&s.htb[ks*32 + 8*g];
    f32x4 a2a = {0,0,0,0}, a2b = {0,0,0,0}, a3a = {0,0,0,0}, a3b = {0,0,0,0};
    a2a = __builtin_amdgcn_mfma_f32_16x16x32_bf16(av[0], w2cf[0], a2a, 0,0,0);
    a3a = __builtin_amdgcn_mfma_f32_16x16x32_bf16(av[0], w3cf[0], a3a, 0,0,0);
    a2b = __builtin_amdgcn_mfma_f32_16x16x32_bf16(av[1], w2cf[1], a2b, 0,0,0);
    a3b = __builtin_amdgcn_mfma_f32_16x16x32_bf16(av[1], w3cf[1], a3b, 0,0,0);
    a2a = __builtin_amdgcn_mfma_f32_16x16x32_bf16(av[2], w2cf[2], a2a, 0,0,0);
    a3a = __builtin_amdgcn_mfma_f32_16x16x32_bf16(av[2], w3cf[2], a3a, 0,0,0);
    a2b = __builtin_amdgcn_mfma_f32_16x16x32_bf16(av[3], w2cf[3], a2b, 0,0,0);
    a3b = __builtin_amdgcn_mfma_f32_16x16x32_bf16(av[3], w3cf[3], a3b, 0,0,0);
    // all lanes hold o2/o3 for col j (broadcast-A => all D rows equal)
    float kp = tanh_f(a2a[0] + a2b[0] + l2v);
    float rr = sigf (a3a[0] + a3b[0] + l3v);
    float kc = rr*(kp + 1.f)*0.5f;
    if (g == 0) s.kcb[j] = f2b(kc);

    // h-part MFMAs (independent of GEMV; fill the pipe)
    bf16x8 af[4][4];
#pragma unroll
    for (int mt = 0; mt < 4; ++mt)
#pragma unroll
      for (int ks = 0; ks < 4; ++ks)
        af[mt][ks] = *(const bf16x8*)&s.hb[cur][(mt*16 + li)*HBS + ks*32 + 8*g];
    f32x4 acc[4] = {{0,0,0,0},{0,0,0,0},{0,0,0,0},{0,0,0,0}};
#pragma unroll
    for (int ks = 0; ks < 4; ++ks)
#pragma unroll
      for (int mt = 0; mt < 4; ++mt)
        acc[mt] = __builtin_amdgcn_mfma_f32_16x16x32_bf16(af[mt][ks], w4f[ks], acc[mt], 0,0,0);

    // coalesced H copy of previous step's h (fused sigmoid)
    if (t >= 1){
      float* Ho = H + ((size_t)t*B_ + b)*8192;
#pragma unroll
      for (int k = 0; k < 4; ++k){
        int f = tid + k*512;                 // float4 index in [0,2048)
        int n = f >> 5, d = (f & 31)*4;
        f32x4 v = *(const f32x4*)&s.hfs[n*HFS + d];
        v[0] = sigf(v[0]); v[1] = sigf(v[1]); v[2] = sigf(v[2]); v[3] = sigf(v[3]);
        *(f32x4*)&Ho[n*128 + d] = v;
      }
    }
    // qc/qn for epilogue
    f32x4 qc4[4], qn4[4];
#pragma unroll
    for (int mt = 0; mt < 4; ++mt){
      qc4[mt] = *(const f32x4*)&s.qe[t%3][mt*16 + g*4];
      qn4[mt] = *(const f32x4*)&s.qe[(t+1)%3][mt*16 + g*4];
    }
    bar_lds();                              // B1: kcb visible

    // ---- C phase ----
    bf16x8 kf[4];
#pragma unroll
    for (int ks = 0; ks < 4; ++ks) kf[ks] = *(const bf16x8*)&s.kcb[ks*32 + 8*g];
    f32x4 acck = {0,0,0,0};
#pragma unroll
    for (int ks = 0; ks < 4; ++ks)
      acck = __builtin_amdgcn_mfma_f32_16x16x32_bf16(kf[ks], w4f[ks+4], acck, 0,0,0);
    // acck rows all equal (broadcast A) -> acck[0]

    float part = 0.f;
#pragma unroll
    for (int mt = 0; mt < 4; ++mt){
#pragma unroll
      for (int r = 0; r < 4; ++r){
        int n = mt*16 + g*4 + r;             // C/D: row=(lane>>4)*4+r, col=lane&15
        float sg = sigf(acc[mt][r] + acck[0] + b4v);
        float hn = fmaf(qc4[mt][r], kc, sg*hreg[mt][r]);
        hreg[mt][r] = hn;
        s.hfs[n*HFS + j]     = hn;
        s.hb[nxt][n*HBS + j] = f2b(hn);
        part = fmaf(qn4[mt][r], hn, part);
      }
    }
    part += __shfl_xor(part, 16);
    part += __shfl_xor(part, 32);
    if (g == 0){
      unsigned short hb16 = f2b(part);
      s.htb[j] = hb16;
      HTg[((size_t)b*T_ + t + 1)*128 + j] = hb16;
    }
    if (tid < 64 && t+2 < T_) s.qe[(t+2)%3][tid] = qmxv;
    l2v = b2f(l2n); l3v = b2f(l3n);
    bar_lds();                              // B2: htb/hb[nxt]/hfs/qe visible
  }
}

// ---------------- ypost: deferred y GEMV over all (b, tau>=1) --------------------
__global__ __launch_bounds__(256) void ypost_k(
    const float* __restrict__ oqe, const unsigned short* __restrict__ HT,
    const float* __restrict__ W5, const float* __restrict__ b5,
    float* __restrict__ pred)
{
  __shared__ float X[32][256];
  __shared__ float w5c[128][33];
  const int tau = blockIdx.x + 1;
  const int tid = threadIdx.x;

  for (int i = tid; i < 32*128; i += 256){
    int bb = i >> 7, k = i & 127;
    X[bb][k] = oqe[((size_t)bb*T_ + tau)*128 + k];
    X[bb][128 + k] = b2f(HT[((size_t)bb*T_ + tau)*128 + k]);
  }
  const int j = tid & 127, rh = tid >> 7;
  float acc[16];
  float base = b5[j];
#pragma unroll
  for (int r = 0; r < 16; ++r) acc[r] = base;
  for (int c = 0; c < 8; ++c){
    __syncthreads();
    for (int i = tid; i < 128*32; i += 256){
      int jj = i >> 5, kk = i & 31;
      w5c[jj][kk] = W5[(size_t)jj*256 + c*32 + kk];
    }
    __syncthreads();
#pragma unroll 8
    for (int k = 0; k < 32; ++k){
      float wv = w5c[j][k];
#pragma unroll
      for (int r = 0; r < 16; ++r) acc[r] = fmaf(X[rh*16 + r][c*32 + k], wv, acc[r]);
    }
  }
  __syncthreads();
#pragma unroll
  for (int r = 0; r < 16; ++r) X[rh*16 + r][j] = sigf(acc[r]);
  __syncthreads();
  if (tid < 32){
    float ssum = 0.f;
    for (int k = 0; k < 128; ++k) ssum += X[tid][k];
    pred[tid*T_ + tau] = ssum * (1.f/128.f);
  }
}

extern "C" void kernel_launch(void* const* d_in, const int* in_sizes, int n_in,
                              void* d_out, int out_size, void* d_ws, size_t ws_size,
                              hipStream_t stream)
{
  const int*   qd  = (const int*)  d_in[0];
  const float* ad  = (const float*)d_in[1];
  const float* qmx = (const float*)d_in[2];
  const float* qew = (const float*)d_in[3];
  const float* W1  = (const float*)d_in[4];
  const float* b1  = (const float*)d_in[5];
  const float* W2  = (const float*)d_in[6];
  const float* b2  = (const float*)d_in[7];
  const float* W3  = (const float*)d_in[8];
  const float* b3  = (const float*)d_in[9];
  const float* W4  = (const float*)d_in[10];
  const float* b4  = (const float*)d_in[11];
  const float* W5  = (const float*)d_in[12];
  const float* b5  = (const float*)d_in[13];
  const float* h0  = (const float*)d_in[14];

  float* H    = (float*)d_out;                         // [127][32][64][128]
  float* pred = H    + (size_t)127*32*64*128;          // [32][128]
  float* oqe  = pred + (size_t)32*128;                 // [32][128][128]
  float* oqa  = oqe  + (size_t)32*128*128;             // [32][128][128]

  unsigned short* W2b = (unsigned short*)d_ws;         // [128][384] bf16
  unsigned short* W3b = W2b + 128*384;                 // [128][384] bf16
  unsigned short* W4b = W3b + 128*384;                 // [128][256] bf16
  unsigned short* HTg = W4b + 128*256;                 // [32][128][128] bf16 h_tilde
  unsigned short* L2b = HTg + (size_t)32*128*128;      // [32][127][128] bf16
  unsigned short* L3b = L2b + (size_t)32*127*128;      // [32][127][128] bf16
  float*          S   = (float*)(L3b + (size_t)32*127*128);  // [128]

  stage_k<<<192, 256, 0, stream>>>(W2, W3, W4, W1, W2b, W3b, W4b, S);
  prep_k <<<256, 256, 0, stream>>>(qd, ad, qew, W1, b1, S, oqe, oqa, pred);
  l23_k  <<<32,  512, 0, stream>>>(oqa, W2b, W3b, b2, b3, L2b, L3b);
  recur_k<<<32,  512, 0, stream>>>(qd, qmx, h0, b4, W2b, W3b, W4b, L2b, L3b, H, HTg);
  ypost_k<<<127, 256, 0, stream>>>(oqe, HTg, W5, b5, pred);
}

// Round 6
// 395.318 us; speedup vs baseline: 1.8900x; 1.0326x over previous
//
#include <hip/hip_runtime.h>

// Problem constants: B=32, T=128, NQ=1000, NC=64, DK=128, DA=128
#define B_  32
#define T_  128
#define HBS 136   // h bf16 LDS row stride (ushorts); rows 272B, 16B-aligned

typedef __attribute__((ext_vector_type(8))) short bf16x8;
typedef __attribute__((ext_vector_type(4))) float f32x4;
typedef __attribute__((ext_vector_type(4))) unsigned short u16x4;

__device__ __forceinline__ float sigf(float x){ return __builtin_amdgcn_rcpf(1.f + __expf(-x)); }
__device__ __forceinline__ float tanh_f(float x){ return 2.f*__builtin_amdgcn_rcpf(1.f + __expf(-2.f*x)) - 1.f; }
__device__ __forceinline__ unsigned short f2b(float x){
  union { float f; unsigned int u; } v; v.f = x;
  return (unsigned short)((v.u + 0x7FFFu + ((v.u >> 16) & 1u)) >> 16);  // RNE bf16
}
__device__ __forceinline__ float b2f(unsigned short u){
  union { unsigned int x; float f; } v; v.x = ((unsigned int)u) << 16; return v.f;
}
// LDS-only barrier: skip the vmcnt(0) drain __syncthreads() emits.
__device__ __forceinline__ void bar_lds(){
  __builtin_amdgcn_sched_barrier(0);
  asm volatile("s_waitcnt lgkmcnt(0)" ::: "memory");
  __builtin_amdgcn_s_barrier();
  __builtin_amdgcn_sched_barrier(0);
}

// ---------------- stage: bf16 weight copies + a-part rowsum of W1 ----------------
__global__ __launch_bounds__(256) void stage_k(
    const float* __restrict__ W2, const float* __restrict__ W3,
    const float* __restrict__ W4, const float* __restrict__ W5,
    const float* __restrict__ W1,
    unsigned short* __restrict__ W2b, unsigned short* __restrict__ W3b,
    unsigned short* __restrict__ W4b, unsigned short* __restrict__ W5b,
    float* __restrict__ S)
{
  int i = blockIdx.x*256 + threadIdx.x;
  if (i < 128*384){ W2b[i] = f2b(W2[i]); W3b[i] = f2b(W3[i]); }
  if (i < 128*256){ W4b[i] = f2b(W4[i]); W5b[i] = f2b(W5[i]); }
  if (i < 128){
    float s = 0.f;
    const float* row = W1 + (size_t)i*256 + 128;
    for (int k = 0; k < 128; ++k) s += row[k];
    S[i] = s;   // sum_k W1[i][128+k]  (a_rep constant along DA)
  }
}

// ---------------- prep: q_emb gather, qa GEMM (fp32 exact), pred[:,0]=0 ----------
__global__ __launch_bounds__(256) void prep_k(
    const int* __restrict__ qd, const float* __restrict__ ad,
    const float* __restrict__ qew, const float* __restrict__ W1,
    const float* __restrict__ b1, const float* __restrict__ S,
    float* __restrict__ oqe, float* __restrict__ oqa, float* __restrict__ pred)
{
  __shared__ float qe[16][128];
  __shared__ float w1c[128][65];
  const int tid = threadIdx.x;
  const int bt0 = blockIdx.x * 16;

  for (int i = tid; i < 16*128; i += 256){
    int r = i >> 7, d = i & 127;
    float v = qew[(size_t)qd[bt0 + r]*128 + d];
    qe[r][d] = v;
    oqe[(size_t)(bt0 + r)*128 + d] = v;
  }
  const int j = tid & 127, rh = tid >> 7;
  float accv[8];
  {
    float base = b1[j], Sj = S[j];
#pragma unroll
    for (int r = 0; r < 8; ++r) accv[r] = fmaf(ad[bt0 + rh*8 + r], Sj, base);
  }
  for (int c = 0; c < 2; ++c){
    __syncthreads();
    for (int i = tid; i < 128*64; i += 256){
      int jj = i >> 6, kk = i & 63;
      w1c[jj][kk] = W1[(size_t)jj*256 + c*64 + kk];
    }
    __syncthreads();
#pragma unroll 4
    for (int k = 0; k < 64; ++k){
      float wv = w1c[j][k];
#pragma unroll
      for (int r = 0; r < 8; ++r) accv[r] = fmaf(qe[rh*8 + r][c*64 + k], wv, accv[r]);
    }
  }
#pragma unroll
  for (int r = 0; r < 8; ++r) oqa[(size_t)(bt0 + rh*8 + r)*128 + j] = accv[r];
  if (blockIdx.x == 0 && tid < 32) pred[tid * T_] = 0.f;
}

// ---------------- l23: precompute learning part of W2/W3 GEMVs -------------------
// L2c[b,t,j] = b2[j] + W2[j,:128]@qa[b,t-1] + W2[j,128:256]@qa[b,t]  (qa[-1]=0)
__global__ __launch_bounds__(512) void l23_k(
    const float* __restrict__ oqa,
    const unsigned short* __restrict__ W2b, const unsigned short* __restrict__ W3b,
    const float* __restrict__ b2, const float* __restrict__ b3,
    unsigned short* __restrict__ L2b, unsigned short* __restrict__ L3b)
{
  __shared__ unsigned short qab[129*136];   // row r = qa[b, r-1]; row 0 = zeros
  const int b = blockIdx.x, tid = threadIdx.x;
  const int w = tid >> 6, lane = tid & 63, g = lane >> 4, li = lane & 15;
  const int mw = w & 3, nw = w >> 2;

  for (int i = tid; i < 129*128; i += 512){
    int row = i >> 7, k = i & 127;
    qab[row*136 + k] = row ? f2b(oqa[((size_t)b*T_ + row-1)*128 + k]) : (unsigned short)0;
  }
  __syncthreads();

  const unsigned short* Wp[2] = {W2b, W3b};
  const float*          bp[2] = {b2, b3};
  unsigned short*       Lp[2] = {L2b, L3b};
#pragma unroll
  for (int m_ = 0; m_ < 2; ++m_){
    bf16x8 bfr[4][8];
#pragma unroll
    for (int nt4 = 0; nt4 < 4; ++nt4){
      int j = (nw*4 + nt4)*16 + li;
#pragma unroll
      for (int ks = 0; ks < 8; ++ks)
        bfr[nt4][ks] = *(const bf16x8*)(Wp[m_] + (size_t)j*384 + ks*32 + 8*g);
    }
    f32x4 acc[2][4] = {{{0,0,0,0},{0,0,0,0},{0,0,0,0},{0,0,0,0}},
                       {{0,0,0,0},{0,0,0,0},{0,0,0,0},{0,0,0,0}}};
#pragma unroll
    for (int mt2 = 0; mt2 < 2; ++mt2){
      int row = (mw*2 + mt2)*16 + li;
      bf16x8 afr[8];
#pragma unroll
      for (int ks = 0; ks < 4; ++ks){
        afr[ks]   = *(const bf16x8*)&qab[ row   *136 + ks*32 + 8*g];
        afr[ks+4] = *(const bf16x8*)&qab[(row+1)*136 + ks*32 + 8*g];
      }
#pragma unroll
      for (int ks = 0; ks < 8; ++ks)
#pragma unroll
        for (int nt4 = 0; nt4 < 4; ++nt4)
          acc[mt2][nt4] = __builtin_amdgcn_mfma_f32_16x16x32_bf16(afr[ks], bfr[nt4][ks], acc[mt2][nt4], 0,0,0);
    }
    float bias[4];
#pragma unroll
    for (int nt4 = 0; nt4 < 4; ++nt4) bias[nt4] = bp[m_][(nw*4 + nt4)*16 + li];
#pragma unroll
    for (int mt2 = 0; mt2 < 2; ++mt2)
#pragma unroll
      for (int nt4 = 0; nt4 < 4; ++nt4)
#pragma unroll
        for (int r = 0; r < 4; ++r){
          int t = (mw*2 + mt2)*16 + g*4 + r;
          int j = (nw*4 + nt4)*16 + li;
          if (t < 127) Lp[m_][((size_t)b*127 + t)*128 + j] = f2b(acc[mt2][nt4][r] + bias[nt4]);
        }
  }
}

// ---------------- recur: 127-step recurrence, one block per batch -----------------
// Wave w owns output cols j = w*16+li (all 64 rows). Thread owns h(n,j) for
// n = mt*16 + g*4 + r. kc for col j in-register; y fused via W5-resident frags.
struct __align__(16) SmR {
  unsigned short hb[2][64*HBS]; // bf16 h, double-buffered (MFMA A operand)
  float qe[3][64];              // qm rows, triple-buffered
  float yp[8];                  // per-wave y partials
  unsigned short htb[128];      // h_tilde bf16 (GEMV A operand, broadcast)
  unsigned short kcb[128];      // KC bf16 (GEMM A operand, broadcast)
  unsigned short ybq[128];      // qemb(t) bf16 (y A operand, broadcast)
  int qdl[T_];
};

__global__ __launch_bounds__(512) void recur_k(
    const int* __restrict__ qd, const float* __restrict__ qmx,
    const float* __restrict__ h0, const float* __restrict__ b4,
    const float* __restrict__ b5,
    const unsigned short* __restrict__ W2b, const unsigned short* __restrict__ W3b,
    const unsigned short* __restrict__ W4b, const unsigned short* __restrict__ W5b,
    const unsigned short* __restrict__ L2b, const unsigned short* __restrict__ L3b,
    const float* __restrict__ oqe,
    float* __restrict__ H, float* __restrict__ pred)
{
  __shared__ SmR s;
  const int b   = blockIdx.x;
  const int tid = threadIdx.x;
  const int w = tid >> 6, lane = tid & 63, g = lane >> 4, li = lane & 15;
  const int j = w*16 + li;

  // ---- register-resident weights
  bf16x8 w2cf[4], w3cf[4];      // W2/W3[:, 256:384] rows j (h_tilde slice)
#pragma unroll
  for (int ks = 0; ks < 4; ++ks){
    w2cf[ks] = *(const bf16x8*)(W2b + (size_t)j*384 + 256 + ks*32 + 8*g);
    w3cf[ks] = *(const bf16x8*)(W3b + (size_t)j*384 + 256 + ks*32 + 8*g);
  }
  bf16x8 w4f[8];                // W4 rows j, K=256
#pragma unroll
  for (int ks = 0; ks < 8; ++ks)
    w4f[ks] = *(const bf16x8*)(W4b + (size_t)j*256 + ks*32 + 8*g);
  bf16x8 w5f[8];                // W5 rows j, K=256 ([qemb | ht])
#pragma unroll
  for (int ks = 0; ks < 8; ++ks)
    w5f[ks] = *(const bf16x8*)(W5b + (size_t)j*256 + ks*32 + 8*g);
  const float b4v = b4[j], b5v = b5[j];

  // ---- fp32 h state in registers: hreg[mt][r] = h(mt*16+g*4+r, j)
  float hreg[4][4];
#pragma unroll
  for (int mt = 0; mt < 4; ++mt)
#pragma unroll
    for (int r = 0; r < 4; ++r)
      hreg[mt][r] = h0[(mt*16 + g*4 + r)*128 + j];

  // ---- init
  for (int i = tid; i < 64*128; i += 512){
    int n = i >> 7, d = i & 127;
    float v = h0[i];
    s.hb[0][n*HBS + d] = f2b(v);
    H[(size_t)b*8192 + i] = sigf(v);
  }
  if (tid < T_) s.qdl[tid] = qd[b*T_ + tid];
  if (tid < 128) s.ybq[tid] = 0;
  __syncthreads();
  if (tid < 64){
    s.qe[0][tid] = qmx[(size_t)s.qdl[0]*64 + tid];
    s.qe[1][tid] = qmx[(size_t)s.qdl[1]*64 + tid];
  }
  __syncthreads();
  if (tid < 128){   // h_tilde0
    float acc = 0.f;
    for (int n = 0; n < 64; ++n) acc = fmaf(s.qe[0][n], h0[n*128 + tid], acc);
    s.htb[tid] = f2b(acc);
  }
  __syncthreads();

  float l2v = b2f(L2b[((size_t)b*127)*128 + j]);
  float l3v = b2f(L3b[((size_t)b*127)*128 + j]);

#pragma unroll 1
  for (int t = 0; t < T_-1; ++t){
    const int cur = t & 1, nxt = cur ^ 1;

    // ================= AB phase =================
    // global prefetches (consumed end of C / next step)
    int tp1 = (t+1 < 127) ? t+1 : 126;
    unsigned short l2n = L2b[((size_t)b*127 + tp1)*128 + j];
    unsigned short l3n = L3b[((size_t)b*127 + tp1)*128 + j];
    float qmxv = 0.f, qen = 0.f;
    if (tid < 64 && t+2 < T_) qmxv = qmx[(size_t)s.qdl[t+2]*64 + tid];
    if (tid < 128)            qen  = oqe[((size_t)b*T_ + t+1)*128 + tid];

    // h_tilde fragments (shared by kc-GEMV and y-GEMV)
    bf16x8 av[4];
#pragma unroll
    for (int ks = 0; ks < 4; ++ks) av[ks] = *(const bf16x8*)&s.htb[ks*32 + 8*g];

    // kc GEMV: 8 independent MFMAs (chain length 1)
    f32x4 q2[4], q3[4];
#pragma unroll
    for (int ks = 0; ks < 4; ++ks){
      f32x4 z = {0,0,0,0};
      q2[ks] = __builtin_amdgcn_mfma_f32_16x16x32_bf16(av[ks], w2cf[ks], z, 0,0,0);
      q3[ks] = __builtin_amdgcn_mfma_f32_16x16x32_bf16(av[ks], w3cf[ks], z, 0,0,0);
    }
    float kp = tanh_f((q2[0][0]+q2[1][0]) + (q2[2][0]+q2[3][0]) + l2v);
    float rr = sigf ((q3[0][0]+q3[1][0]) + (q3[2][0]+q3[3][0]) + l3v);
    float kc = rr*(kp + 1.f)*0.5f;
    if (g == 0) s.kcb[j] = f2b(kc);

    // y GEMV for pred[b,t]: [qemb(t) | h_tilde(t)] @ W5^T, 8 indep MFMAs
    {
      bf16x8 yq[4];
#pragma unroll
      for (int ks = 0; ks < 4; ++ks) yq[ks] = *(const bf16x8*)&s.ybq[ks*32 + 8*g];
      f32x4 y_[8];
#pragma unroll
      for (int ks = 0; ks < 4; ++ks){
        f32x4 z = {0,0,0,0};
        y_[ks]   = __builtin_amdgcn_mfma_f32_16x16x32_bf16(yq[ks], w5f[ks],   z, 0,0,0);
        y_[ks+4] = __builtin_amdgcn_mfma_f32_16x16x32_bf16(av[ks], w5f[ks+4], z, 0,0,0);
      }
      float o5 = ((y_[0][0]+y_[1][0]) + (y_[2][0]+y_[3][0]))
               + ((y_[4][0]+y_[5][0]) + (y_[6][0]+y_[7][0]));
      float sv = sigf(o5 + b5v);
      sv += __shfl_xor(sv, 1); sv += __shfl_xor(sv, 2);
      sv += __shfl_xor(sv, 4); sv += __shfl_xor(sv, 8);
      if (lane == 0) s.yp[w] = sv;
    }

    // h-part GEMM (throughput work, 16 MFMAs)
    bf16x8 af[4][4];
#pragma unroll
    for (int mt = 0; mt < 4; ++mt)
#pragma unroll
      for (int ks = 0; ks < 4; ++ks)
        af[mt][ks] = *(const bf16x8*)&s.hb[cur][(mt*16 + li)*HBS + ks*32 + 8*g];
    f32x4 acc[4] = {{0,0,0,0},{0,0,0,0},{0,0,0,0},{0,0,0,0}};
#pragma unroll
    for (int ks = 0; ks < 4; ++ks)
#pragma unroll
      for (int mt = 0; mt < 4; ++mt)
        acc[mt] = __builtin_amdgcn_mfma_f32_16x16x32_bf16(af[mt][ks], w4f[ks], acc[mt], 0,0,0);

    // coalesced H copy of h(t) from hb[cur] (fused bf16->f32 + sigmoid)
    if (t >= 1){
      float* Ho = H + ((size_t)t*B_ + b)*8192;
#pragma unroll
      for (int k = 0; k < 4; ++k){
        int c = tid + k*512;                  // ushort4 chunk in [0,2048)
        int n = c >> 5, o = (c & 31)*4;
        u16x4 hv = *(const u16x4*)&s.hb[cur][n*HBS + o];
        f32x4 v;
        v[0] = sigf(b2f(hv[0])); v[1] = sigf(b2f(hv[1]));
        v[2] = sigf(b2f(hv[2])); v[3] = sigf(b2f(hv[3]));
        *(f32x4*)&Ho[n*128 + o] = v;
      }
    }
    // qc/qn for epilogue
    f32x4 qc4[4], qn4[4];
#pragma unroll
    for (int mt = 0; mt < 4; ++mt){
      qc4[mt] = *(const f32x4*)&s.qe[t%3][mt*16 + g*4];
      qn4[mt] = *(const f32x4*)&s.qe[(t+1)%3][mt*16 + g*4];
    }
    bar_lds();                              // B1: kcb/yp visible

    // ================= C phase =================
    bf16x8 kf[4];
#pragma unroll
    for (int ks = 0; ks < 4; ++ks) kf[ks] = *(const bf16x8*)&s.kcb[ks*32 + 8*g];
    f32x4 zk[4];
#pragma unroll
    for (int ks = 0; ks < 4; ++ks){
      f32x4 z = {0,0,0,0};
      zk[ks] = __builtin_amdgcn_mfma_f32_16x16x32_bf16(kf[ks], w4f[ks+4], z, 0,0,0);
    }
    float ack = (zk[0][0]+zk[1][0]) + (zk[2][0]+zk[3][0]);

    float part = 0.f;
#pragma unroll
    for (int mt = 0; mt < 4; ++mt){
#pragma unroll
      for (int r = 0; r < 4; ++r){
        int n = mt*16 + g*4 + r;             // C/D: row=(lane>>4)*4+r, col=lane&15
        float sg = sigf(acc[mt][r] + ack + b4v);
        float hn = fmaf(qc4[mt][r], kc, sg*hreg[mt][r]);
        hreg[mt][r] = hn;
        s.hb[nxt][n*HBS + j] = f2b(hn);
        part = fmaf(qn4[mt][r], hn, part);
      }
    }
    part += __shfl_xor(part, 16);
    part += __shfl_xor(part, 32);
    if (g == 0) s.htb[j] = f2b(part);

    // y reduce -> pred[b,t]
    if (w == 0 && lane < 8){
      float v = s.yp[lane];
      v += __shfl_xor(v, 4); v += __shfl_xor(v, 2); v += __shfl_xor(v, 1);
      if (lane == 0 && t >= 1) pred[b*T_ + t] = v * (1.f/128.f);
    }
    if (tid < 128) s.ybq[tid] = f2b(qen);
    if (tid < 64 && t+2 < T_) s.qe[(t+2)%3][tid] = qmxv;
    l2v = b2f(l2n); l3v = b2f(l3n);
    bar_lds();                              // B2: htb/hb[nxt]/ybq/qe visible
  }

  // ---- tail: pred[b,127] from h_tilde(127) + qemb(127)
  {
    bf16x8 av[4], yq[4];
#pragma unroll
    for (int ks = 0; ks < 4; ++ks){
      av[ks] = *(const bf16x8*)&s.htb[ks*32 + 8*g];
      yq[ks] = *(const bf16x8*)&s.ybq[ks*32 + 8*g];
    }
    f32x4 y_[8];
#pragma unroll
    for (int ks = 0; ks < 4; ++ks){
      f32x4 z = {0,0,0,0};
      y_[ks]   = __builtin_amdgcn_mfma_f32_16x16x32_bf16(yq[ks], w5f[ks],   z, 0,0,0);
      y_[ks+4] = __builtin_amdgcn_mfma_f32_16x16x32_bf16(av[ks], w5f[ks+4], z, 0,0,0);
    }
    float o5 = ((y_[0][0]+y_[1][0]) + (y_[2][0]+y_[3][0]))
             + ((y_[4][0]+y_[5][0]) + (y_[6][0]+y_[7][0]));
    float sv = sigf(o5 + b5v);
    sv += __shfl_xor(sv, 1); sv += __shfl_xor(sv, 2);
    sv += __shfl_xor(sv, 4); sv += __shfl_xor(sv, 8);
    if (lane == 0) s.yp[w] = sv;
  }
  bar_lds();
  if (w == 0 && lane < 8){
    float v = s.yp[lane];
    v += __shfl_xor(v, 4); v += __shfl_xor(v, 2); v += __shfl_xor(v, 1);
    if (lane == 0) pred[b*T_ + 127] = v * (1.f/128.f);
  }
}

extern "C" void kernel_launch(void* const* d_in, const int* in_sizes, int n_in,
                              void* d_out, int out_size, void* d_ws, size_t ws_size,
                              hipStream_t stream)
{
  const int*   qd  = (const int*)  d_in[0];
  const float* ad  = (const float*)d_in[1];
  const float* qmx = (const float*)d_in[2];
  const float* qew = (const float*)d_in[3];
  const float* W1  = (const float*)d_in[4];
  const float* b1  = (const float*)d_in[5];
  const float* W2  = (const float*)d_in[6];
  const float* b2  = (const float*)d_in[7];
  const float* W3  = (const float*)d_in[8];
  const float* b3  = (const float*)d_in[9];
  const float* W4  = (const float*)d_in[10];
  const float* b4  = (const float*)d_in[11];
  const float* W5  = (const float*)d_in[12];
  const float* b5  = (const float*)d_in[13];
  const float* h0  = (const float*)d_in[14];

  float* H    = (float*)d_out;                         // [127][32][64][128]
  float* pred = H    + (size_t)127*32*64*128;          // [32][128]
  float* oqe  = pred + (size_t)32*128;                 // [32][128][128]
  float* oqa  = oqe  + (size_t)32*128*128;             // [32][128][128]

  unsigned short* W2b = (unsigned short*)d_ws;         // [128][384] bf16
  unsigned short* W3b = W2b + 128*384;                 // [128][384] bf16
  unsigned short* W4b = W3b + 128*384;                 // [128][256] bf16
  unsigned short* W5b = W4b + 128*256;                 // [128][256] bf16
  unsigned short* L2b = W5b + 128*256;                 // [32][127][128] bf16
  unsigned short* L3b = L2b + (size_t)32*127*128;      // [32][127][128] bf16
  float*          S   = (float*)(L3b + (size_t)32*127*128);  // [128]

  stage_k<<<192, 256, 0, stream>>>(W2, W3, W4, W5, W1, W2b, W3b, W4b, W5b, S);
  prep_k <<<256, 256, 0, stream>>>(qd, ad, qew, W1, b1, S, oqe, oqa, pred);
  l23_k  <<<32,  512, 0, stream>>>(oqa, W2b, W3b, b2, b3, L2b, L3b);
  recur_k<<<32,  512, 0, stream>>>(qd, qmx, h0, b4, b5, W2b, W3b, W4b, W5b,
                                   L2b, L3b, oqe, H, pred);
}

// Round 7
// 371.062 us; speedup vs baseline: 2.0136x; 1.0654x over previous
//
#include <hip/hip_runtime.h>

// Problem constants: B=32, T=128, NQ=1000, NC=64, DK=128, DA=128
#define B_  32
#define T_  128
#define HBS 136   // h bf16 LDS row stride (ushorts); rows 272B, 16B-aligned

typedef __attribute__((ext_vector_type(8))) short bf16x8;
typedef __attribute__((ext_vector_type(4))) float f32x4;
typedef __attribute__((ext_vector_type(8))) unsigned short u16x8;

__device__ __forceinline__ float sigf(float x){ return __builtin_amdgcn_rcpf(1.f + __expf(-x)); }
__device__ __forceinline__ float tanh_f(float x){ return 2.f*__builtin_amdgcn_rcpf(1.f + __expf(-2.f*x)) - 1.f; }
__device__ __forceinline__ unsigned short f2b(float x){
  union { float f; unsigned int u; } v; v.f = x;
  return (unsigned short)((v.u + 0x7FFFu + ((v.u >> 16) & 1u)) >> 16);  // RNE bf16
}
__device__ __forceinline__ float b2f(unsigned short u){
  union { unsigned int x; float f; } v; v.x = ((unsigned int)u) << 16; return v.f;
}
// LDS-only barrier: skip the vmcnt(0) drain __syncthreads() emits.
__device__ __forceinline__ void bar_lds(){
  __builtin_amdgcn_sched_barrier(0);
  asm volatile("s_waitcnt lgkmcnt(0)" ::: "memory");
  __builtin_amdgcn_s_barrier();
  __builtin_amdgcn_sched_barrier(0);
}

// ---------------- stage: bf16 weight copies + a-part rowsum of W1 ----------------
__global__ __launch_bounds__(256) void stage_k(
    const float* __restrict__ W2, const float* __restrict__ W3,
    const float* __restrict__ W4, const float* __restrict__ W1,
    unsigned short* __restrict__ W2b, unsigned short* __restrict__ W3b,
    unsigned short* __restrict__ W4b, float* __restrict__ S)
{
  int i = blockIdx.x*256 + threadIdx.x;
  if (i < 128*384){ W2b[i] = f2b(W2[i]); W3b[i] = f2b(W3[i]); }
  if (i < 128*256){ W4b[i] = f2b(W4[i]); }
  if (i < 128){
    float s = 0.f;
    const float* row = W1 + (size_t)i*256 + 128;
    for (int k = 0; k < 128; ++k) s += row[k];
    S[i] = s;   // sum_k W1[i][128+k]  (a_rep constant along DA)
  }
}

// ---------------- prep: q_emb gather, qa GEMM (fp32 exact), pred[:,0]=0 ----------
__global__ __launch_bounds__(256) void prep_k(
    const int* __restrict__ qd, const float* __restrict__ ad,
    const float* __restrict__ qew, const float* __restrict__ W1,
    const float* __restrict__ b1, const float* __restrict__ S,
    float* __restrict__ oqe, float* __restrict__ oqa, float* __restrict__ pred)
{
  __shared__ float qe[16][128];
  __shared__ float w1c[128][65];
  const int tid = threadIdx.x;
  const int bt0 = blockIdx.x * 16;

  for (int i = tid; i < 16*128; i += 256){
    int r = i >> 7, d = i & 127;
    float v = qew[(size_t)qd[bt0 + r]*128 + d];
    qe[r][d] = v;
    oqe[(size_t)(bt0 + r)*128 + d] = v;
  }
  const int j = tid & 127, rh = tid >> 7;
  float accv[8];
  {
    float base = b1[j], Sj = S[j];
#pragma unroll
    for (int r = 0; r < 8; ++r) accv[r] = fmaf(ad[bt0 + rh*8 + r], Sj, base);
  }
  for (int c = 0; c < 2; ++c){
    __syncthreads();
    for (int i = tid; i < 128*64; i += 256){
      int jj = i >> 6, kk = i & 63;
      w1c[jj][kk] = W1[(size_t)jj*256 + c*64 + kk];
    }
    __syncthreads();
#pragma unroll 4
    for (int k = 0; k < 64; ++k){
      float wv = w1c[j][k];
#pragma unroll
      for (int r = 0; r < 8; ++r) accv[r] = fmaf(qe[rh*8 + r][c*64 + k], wv, accv[r]);
    }
  }
#pragma unroll
  for (int r = 0; r < 8; ++r) oqa[(size_t)(bt0 + rh*8 + r)*128 + j] = accv[r];
  if (blockIdx.x == 0 && tid < 32) pred[tid * T_] = 0.f;
}

// ---------------- l23: precompute learning part of W2/W3 GEMVs -------------------
// L2c[b,t,j] = b2[j] + W2[j,:128]@qa[b,t-1] + W2[j,128:256]@qa[b,t]  (qa[-1]=0)
__global__ __launch_bounds__(512) void l23_k(
    const float* __restrict__ oqa,
    const unsigned short* __restrict__ W2b, const unsigned short* __restrict__ W3b,
    const float* __restrict__ b2, const float* __restrict__ b3,
    unsigned short* __restrict__ L2b, unsigned short* __restrict__ L3b)
{
  __shared__ unsigned short qab[129*136];   // row r = qa[b, r-1]; row 0 = zeros
  const int b = blockIdx.x, tid = threadIdx.x;
  const int w = tid >> 6, lane = tid & 63, g = lane >> 4, li = lane & 15;
  const int mw = w & 3, nw = w >> 2;

  for (int i = tid; i < 129*128; i += 512){
    int row = i >> 7, k = i & 127;
    qab[row*136 + k] = row ? f2b(oqa[((size_t)b*T_ + row-1)*128 + k]) : (unsigned short)0;
  }
  __syncthreads();

  const unsigned short* Wp[2] = {W2b, W3b};
  const float*          bp[2] = {b2, b3};
  unsigned short*       Lp[2] = {L2b, L3b};
#pragma unroll
  for (int m_ = 0; m_ < 2; ++m_){
    bf16x8 bfr[4][8];
#pragma unroll
    for (int nt4 = 0; nt4 < 4; ++nt4){
      int j = (nw*4 + nt4)*16 + li;
#pragma unroll
      for (int ks = 0; ks < 8; ++ks)
        bfr[nt4][ks] = *(const bf16x8*)(Wp[m_] + (size_t)j*384 + ks*32 + 8*g);
    }
    f32x4 acc[2][4] = {{{0,0,0,0},{0,0,0,0},{0,0,0,0},{0,0,0,0}},
                       {{0,0,0,0},{0,0,0,0},{0,0,0,0},{0,0,0,0}}};
#pragma unroll
    for (int mt2 = 0; mt2 < 2; ++mt2){
      int row = (mw*2 + mt2)*16 + li;
      bf16x8 afr[8];
#pragma unroll
      for (int ks = 0; ks < 4; ++ks){
        afr[ks]   = *(const bf16x8*)&qab[ row   *136 + ks*32 + 8*g];
        afr[ks+4] = *(const bf16x8*)&qab[(row+1)*136 + ks*32 + 8*g];
      }
#pragma unroll
      for (int ks = 0; ks < 8; ++ks)
#pragma unroll
        for (int nt4 = 0; nt4 < 4; ++nt4)
          acc[mt2][nt4] = __builtin_amdgcn_mfma_f32_16x16x32_bf16(afr[ks], bfr[nt4][ks], acc[mt2][nt4], 0,0,0);
    }
    float bias[4];
#pragma unroll
    for (int nt4 = 0; nt4 < 4; ++nt4) bias[nt4] = bp[m_][(nw*4 + nt4)*16 + li];
#pragma unroll
    for (int mt2 = 0; mt2 < 2; ++mt2)
#pragma unroll
      for (int nt4 = 0; nt4 < 4; ++nt4)
#pragma unroll
        for (int r = 0; r < 4; ++r){
          int t = (mw*2 + mt2)*16 + g*4 + r;
          int j = (nw*4 + nt4)*16 + li;
          if (t < 127) Lp[m_][((size_t)b*127 + t)*128 + j] = f2b(acc[mt2][nt4][r] + bias[nt4]);
        }
  }
}

// ---------------- recur: 127-step recurrence, one block per batch -----------------
// Wave w owns output cols j = w*16+li (all 64 rows). Thread owns h(n,j) for
// n = mt*16 + g*4 + r. kc for col j in-register. H exported as RAW bf16 into the
// first half of each f32 H slice; hexp_k expands+sigmoids in place.
struct __align__(16) SmR {
  unsigned short hb[2][64*HBS]; // bf16 h, double-buffered (MFMA A operand)
  float qe[3][64];              // qm rows, triple-buffered
  unsigned short htb[128];      // h_tilde bf16 (GEMV A operand, broadcast)
  unsigned short kcb[128];      // KC bf16 (GEMM A operand, broadcast)
  int qdl[T_];
};

__global__ __launch_bounds__(512) void recur_k(
    const int* __restrict__ qd, const float* __restrict__ qmx,
    const float* __restrict__ h0, const float* __restrict__ b4,
    const unsigned short* __restrict__ W2b, const unsigned short* __restrict__ W3b,
    const unsigned short* __restrict__ W4b,
    const unsigned short* __restrict__ L2b, const unsigned short* __restrict__ L3b,
    float* __restrict__ H, unsigned short* __restrict__ HTg)
{
  __shared__ SmR s;
  const int b   = blockIdx.x;
  const int tid = threadIdx.x;
  const int w = tid >> 6, lane = tid & 63, g = lane >> 4, li = lane & 15;
  const int j = w*16 + li;

  // ---- register-resident weights
  bf16x8 w2cf[4], w3cf[4];      // W2/W3[:, 256:384] rows j (h_tilde slice)
#pragma unroll
  for (int ks = 0; ks < 4; ++ks){
    w2cf[ks] = *(const bf16x8*)(W2b + (size_t)j*384 + 256 + ks*32 + 8*g);
    w3cf[ks] = *(const bf16x8*)(W3b + (size_t)j*384 + 256 + ks*32 + 8*g);
  }
  bf16x8 w4f[8];                // W4 rows j, K=256
#pragma unroll
  for (int ks = 0; ks < 8; ++ks)
    w4f[ks] = *(const bf16x8*)(W4b + (size_t)j*256 + ks*32 + 8*g);
  const float b4v = b4[j];

  // ---- fp32 h state in registers: hreg[mt][r] = h(mt*16+g*4+r, j)
  float hreg[4][4];
#pragma unroll
  for (int mt = 0; mt < 4; ++mt)
#pragma unroll
    for (int r = 0; r < 4; ++r)
      hreg[mt][r] = h0[(mt*16 + g*4 + r)*128 + j];

  // ---- init
  for (int i = tid; i < 64*128; i += 512){
    int n = i >> 7, d = i & 127;
    float v = h0[i];
    s.hb[0][n*HBS + d] = f2b(v);
    H[(size_t)b*8192 + i] = sigf(v);   // H[0] slice, fp32 directly
  }
  if (tid < T_) s.qdl[tid] = qd[b*T_ + tid];
  __syncthreads();
  if (tid < 64){
    s.qe[0][tid] = qmx[(size_t)s.qdl[0]*64 + tid];
    s.qe[1][tid] = qmx[(size_t)s.qdl[1]*64 + tid];
  }
  __syncthreads();
  if (tid < 128){   // h_tilde0
    float acc = 0.f;
    for (int n = 0; n < 64; ++n) acc = fmaf(s.qe[0][n], h0[n*128 + tid], acc);
    s.htb[tid] = f2b(acc);
  }
  __syncthreads();

  float l2v = b2f(L2b[((size_t)b*127)*128 + j]);
  float l3v = b2f(L3b[((size_t)b*127)*128 + j]);
  f32x4 qc4[4];
#pragma unroll
  for (int mt = 0; mt < 4; ++mt) qc4[mt] = *(const f32x4*)&s.qe[0][mt*16 + g*4];

#pragma unroll 1
  for (int t = 0; t < T_-1; ++t){
    const int cur = t & 1, nxt = cur ^ 1;

    // ================= AB phase =================
    // global prefetches (consumed end of C / next step)
    int tp1 = (t+1 < 127) ? t+1 : 126;
    unsigned short l2n = L2b[((size_t)b*127 + tp1)*128 + j];
    unsigned short l3n = L3b[((size_t)b*127 + tp1)*128 + j];
    float qmxv = 0.f;
    if (tid < 64 && t+2 < T_) qmxv = qmx[(size_t)s.qdl[t+2]*64 + tid];

    // kc GEMV: 8 independent MFMAs (chain length 1)
    bf16x8 av[4];
#pragma unroll
    for (int ks = 0; ks < 4; ++ks) av[ks] = *(const bf16x8*)&s.htb[ks*32 + 8*g];
    f32x4 q2[4], q3[4];
#pragma unroll
    for (int ks = 0; ks < 4; ++ks){
      f32x4 z = {0,0,0,0};
      q2[ks] = __builtin_amdgcn_mfma_f32_16x16x32_bf16(av[ks], w2cf[ks], z, 0,0,0);
      q3[ks] = __builtin_amdgcn_mfma_f32_16x16x32_bf16(av[ks], w3cf[ks], z, 0,0,0);
    }
    float kp = tanh_f((q2[0][0]+q2[1][0]) + (q2[2][0]+q2[3][0]) + l2v);
    float rr = sigf ((q3[0][0]+q3[1][0]) + (q3[2][0]+q3[3][0]) + l3v);
    float kc = rr*(kp + 1.f)*0.5f;
    if (g == 0) s.kcb[j] = f2b(kc);

    // h-part GEMM (throughput work, 16 MFMAs)
    bf16x8 af[4][4];
#pragma unroll
    for (int mt = 0; mt < 4; ++mt)
#pragma unroll
      for (int ks = 0; ks < 4; ++ks)
        af[mt][ks] = *(const bf16x8*)&s.hb[cur][(mt*16 + li)*HBS + ks*32 + 8*g];
    f32x4 acc[4] = {{0,0,0,0},{0,0,0,0},{0,0,0,0},{0,0,0,0}};
#pragma unroll
    for (int ks = 0; ks < 4; ++ks)
#pragma unroll
      for (int mt = 0; mt < 4; ++mt)
        acc[mt] = __builtin_amdgcn_mfma_f32_16x16x32_bf16(af[mt][ks], w4f[ks], acc[mt], 0,0,0);

    // coalesced RAW bf16 export of h(t) into the H[t] slice (first half of f32 slot)
    if (t >= 1){
      unsigned short* Hu = (unsigned short*)(H + ((size_t)t*B_ + b)*8192);
#pragma unroll
      for (int k = 0; k < 2; ++k){
        int c = tid + k*512;                  // ushort8 chunk in [0,1024)
        int n = c >> 4, o = (c & 15)*8;
        u16x8 hv = *(const u16x8*)&s.hb[cur][n*HBS + o];
        *(u16x8*)&Hu[c*8] = hv;
      }
    }
    // qn for epilogue (qc rotated from previous step's qn)
    f32x4 qn4[4];
#pragma unroll
    for (int mt = 0; mt < 4; ++mt)
      qn4[mt] = *(const f32x4*)&s.qe[(t+1)%3][mt*16 + g*4];
    bar_lds();                              // B1: kcb visible

    // ================= C phase =================
    bf16x8 kf[4];
#pragma unroll
    for (int ks = 0; ks < 4; ++ks) kf[ks] = *(const bf16x8*)&s.kcb[ks*32 + 8*g];
    f32x4 zk[4];
#pragma unroll
    for (int ks = 0; ks < 4; ++ks){
      f32x4 z = {0,0,0,0};
      zk[ks] = __builtin_amdgcn_mfma_f32_16x16x32_bf16(kf[ks], w4f[ks+4], z, 0,0,0);
    }
    float ack = (zk[0][0]+zk[1][0]) + (zk[2][0]+zk[3][0]);

    float part = 0.f;
#pragma unroll
    for (int mt = 0; mt < 4; ++mt){
#pragma unroll
      for (int r = 0; r < 4; ++r){
        int n = mt*16 + g*4 + r;             // C/D: row=(lane>>4)*4+r, col=lane&15
        float sg = sigf(acc[mt][r] + ack + b4v);
        float hn = fmaf(qc4[mt][r], kc, sg*hreg[mt][r]);
        hreg[mt][r] = hn;
        s.hb[nxt][n*HBS + j] = f2b(hn);
        part = fmaf(qn4[mt][r], hn, part);
      }
    }
    part += __shfl_xor(part, 16);
    part += __shfl_xor(part, 32);
    if (g == 0){
      unsigned short hb16 = f2b(part);
      s.htb[j] = hb16;
      HTg[((size_t)b*T_ + t + 1)*128 + j] = hb16;
    }
    if (tid < 64 && t+2 < T_) s.qe[(t+2)%3][tid] = qmxv;
    l2v = b2f(l2n); l3v = b2f(l3n);
#pragma unroll
    for (int mt = 0; mt < 4; ++mt) qc4[mt] = qn4[mt];
    bar_lds();                              // B2: htb/hb[nxt]/qe visible
  }
}

// ---------------- hexp: in-place bf16 -> sigmoid(f32) expansion of H[1..126] -----
// One block per (t,b) slice. Load the slice's packed bf16 into registers, sync,
// then write f32 — no cross-block overlap, replay-safe.
__global__ __launch_bounds__(256) void hexp_k(float* __restrict__ H)
{
  const int tb = blockIdx.x;
  const int t  = (tb >> 5) + 1, b = tb & 31;
  float* Hs = H + ((size_t)t*B_ + b)*8192;
  const unsigned short* Hu = (const unsigned short*)Hs;
  const int tid = threadIdx.x;

  u16x8 v[4];
#pragma unroll
  for (int k = 0; k < 4; ++k){
    int c = k*256 + tid;                    // ushort8 chunk in [0,1024)
    v[k] = *(const u16x8*)&Hu[c*8];
  }
  __syncthreads();
#pragma unroll
  for (int k = 0; k < 4; ++k){
    int c = k*256 + tid;
    f32x4 lo, hi;
    lo[0]=sigf(b2f(v[k][0])); lo[1]=sigf(b2f(v[k][1]));
    lo[2]=sigf(b2f(v[k][2])); lo[3]=sigf(b2f(v[k][3]));
    hi[0]=sigf(b2f(v[k][4])); hi[1]=sigf(b2f(v[k][5]));
    hi[2]=sigf(b2f(v[k][6])); hi[3]=sigf(b2f(v[k][7]));
    *(f32x4*)&Hs[c*8]     = lo;
    *(f32x4*)&Hs[c*8 + 4] = hi;
  }
}

// ---------------- ypost: deferred y GEMV over all (b, tau>=1) --------------------
__global__ __launch_bounds__(256) void ypost_k(
    const float* __restrict__ oqe, const unsigned short* __restrict__ HT,
    const float* __restrict__ W5, const float* __restrict__ b5,
    float* __restrict__ pred)
{
  __shared__ float X[32][256];
  __shared__ float w5c[128][33];
  const int tau = blockIdx.x + 1;
  const int tid = threadIdx.x;

  for (int i = tid; i < 32*128; i += 256){
    int bb = i >> 7, k = i & 127;
    X[bb][k] = oqe[((size_t)bb*T_ + tau)*128 + k];
    X[bb][128 + k] = b2f(HT[((size_t)bb*T_ + tau)*128 + k]);
  }
  const int j = tid & 127, rh = tid >> 7;
  float acc[16];
  float base = b5[j];
#pragma unroll
  for (int r = 0; r < 16; ++r) acc[r] = base;
  for (int c = 0; c < 8; ++c){
    __syncthreads();
    for (int i = tid; i < 128*32; i += 256){
      int jj = i >> 5, kk = i & 31;
      w5c[jj][kk] = W5[(size_t)jj*256 + c*32 + kk];
    }
    __syncthreads();
#pragma unroll 8
    for (int k = 0; k < 32; ++k){
      float wv = w5c[j][k];
#pragma unroll
      for (int r = 0; r < 16; ++r) acc[r] = fmaf(X[rh*16 + r][c*32 + k], wv, acc[r]);
    }
  }
  __syncthreads();
#pragma unroll
  for (int r = 0; r < 16; ++r) X[rh*16 + r][j] = sigf(acc[r]);
  __syncthreads();
  if (tid < 32){
    float ssum = 0.f;
    for (int k = 0; k < 128; ++k) ssum += X[tid][k];
    pred[tid*T_ + tau] = ssum * (1.f/128.f);
  }
}

extern "C" void kernel_launch(void* const* d_in, const int* in_sizes, int n_in,
                              void* d_out, int out_size, void* d_ws, size_t ws_size,
                              hipStream_t stream)
{
  const int*   qd  = (const int*)  d_in[0];
  const float* ad  = (const float*)d_in[1];
  const float* qmx = (const float*)d_in[2];
  const float* qew = (const float*)d_in[3];
  const float* W1  = (const float*)d_in[4];
  const float* b1  = (const float*)d_in[5];
  const float* W2  = (const float*)d_in[6];
  const float* b2  = (const float*)d_in[7];
  const float* W3  = (const float*)d_in[8];
  const float* b3  = (const float*)d_in[9];
  const float* W4  = (const float*)d_in[10];
  const float* b4  = (const float*)d_in[11];
  const float* W5  = (const float*)d_in[12];
  const float* b5  = (const float*)d_in[13];
  const float* h0  = (const float*)d_in[14];

  float* H    = (float*)d_out;                         // [127][32][64][128]
  float* pred = H    + (size_t)127*32*64*128;          // [32][128]
  float* oqe  = pred + (size_t)32*128;                 // [32][128][128]
  float* oqa  = oqe  + (size_t)32*128*128;             // [32][128][128]

  unsigned short* W2b = (unsigned short*)d_ws;         // [128][384] bf16
  unsigned short* W3b = W2b + 128*384;                 // [128][384] bf16
  unsigned short* W4b = W3b + 128*384;                 // [128][256] bf16
  unsigned short* HTg = W4b + 128*256;                 // [32][128][128] bf16 h_tilde
  unsigned short* L2b = HTg + (size_t)32*128*128;      // [32][127][128] bf16
  unsigned short* L3b = L2b + (size_t)32*127*128;      // [32][127][128] bf16
  float*          S   = (float*)(L3b + (size_t)32*127*128);  // [128]

  stage_k<<<192, 256, 0, stream>>>(W2, W3, W4, W1, W2b, W3b, W4b, S);
  prep_k <<<256, 256, 0, stream>>>(qd, ad, qew, W1, b1, S, oqe, oqa, pred);
  l23_k  <<<32,  512, 0, stream>>>(oqa, W2b, W3b, b2, b3, L2b, L3b);
  recur_k<<<32,  512, 0, stream>>>(qd, qmx, h0, b4, W2b, W3b, W4b,
                                   L2b, L3b, H, HTg);
  hexp_k <<<126*32, 256, 0, stream>>>(H);
  ypost_k<<<127, 256, 0, stream>>>(oqe, HTg, W5, b5, pred);
}

// Round 8
// 336.667 us; speedup vs baseline: 2.2193x; 1.1022x over previous
//
#include <hip/hip_runtime.h>

// Problem constants: B=32, T=128, NQ=1000, NC=64, DK=128, DA=128
#define B_  32
#define T_  128
#define HBS 136   // h bf16 LDS row stride (ushorts); rows 272B, 16B-aligned

typedef __attribute__((ext_vector_type(8))) short bf16x8;
typedef __attribute__((ext_vector_type(4))) float f32x4;
typedef __attribute__((ext_vector_type(8))) unsigned short u16x8;

__device__ __forceinline__ float sigf(float x){ return __builtin_amdgcn_rcpf(1.f + __expf(-x)); }
__device__ __forceinline__ unsigned short f2b(float x){
  union { float f; unsigned int u; } v; v.f = x;
  return (unsigned short)((v.u + 0x7FFFu + ((v.u >> 16) & 1u)) >> 16);  // RNE bf16
}
__device__ __forceinline__ float b2f(unsigned short u){
  union { unsigned int x; float f; } v; v.x = ((unsigned int)u) << 16; return v.f;
}
// LDS-only barrier: skip the vmcnt(0) drain __syncthreads() emits.
__device__ __forceinline__ void bar_lds(){
  __builtin_amdgcn_sched_barrier(0);
  asm volatile("s_waitcnt lgkmcnt(0)" ::: "memory");
  __builtin_amdgcn_s_barrier();
  __builtin_amdgcn_sched_barrier(0);
}

// ---------------- stage: bf16 weight copies + a-part rowsum of W1 ----------------
__global__ __launch_bounds__(256) void stage_k(
    const float* __restrict__ W2, const float* __restrict__ W3,
    const float* __restrict__ W4, const float* __restrict__ W1,
    unsigned short* __restrict__ W2b, unsigned short* __restrict__ W3b,
    unsigned short* __restrict__ W4b, float* __restrict__ S)
{
  int i = blockIdx.x*256 + threadIdx.x;
  if (i < 128*384){ W2b[i] = f2b(W2[i]); W3b[i] = f2b(W3[i]); }
  if (i < 128*256){ W4b[i] = f2b(W4[i]); }
  if (i < 128){
    float s = 0.f;
    const float* row = W1 + (size_t)i*256 + 128;
    for (int k = 0; k < 128; ++k) s += row[k];
    S[i] = s;   // sum_k W1[i][128+k]  (a_rep constant along DA)
  }
}

// ---------------- prep: q_emb gather, qa GEMM (fp32 exact), pred[:,0]=0 ----------
__global__ __launch_bounds__(256) void prep_k(
    const int* __restrict__ qd, const float* __restrict__ ad,
    const float* __restrict__ qew, const float* __restrict__ W1,
    const float* __restrict__ b1, const float* __restrict__ S,
    float* __restrict__ oqe, float* __restrict__ oqa, float* __restrict__ pred)
{
  __shared__ float qe[16][128];
  __shared__ float w1c[128][65];
  const int tid = threadIdx.x;
  const int bt0 = blockIdx.x * 16;

  for (int i = tid; i < 16*128; i += 256){
    int r = i >> 7, d = i & 127;
    float v = qew[(size_t)qd[bt0 + r]*128 + d];
    qe[r][d] = v;
    oqe[(size_t)(bt0 + r)*128 + d] = v;
  }
  const int j = tid & 127, rh = tid >> 7;
  float accv[8];
  {
    float base = b1[j], Sj = S[j];
#pragma unroll
    for (int r = 0; r < 8; ++r) accv[r] = fmaf(ad[bt0 + rh*8 + r], Sj, base);
  }
  for (int c = 0; c < 2; ++c){
    __syncthreads();
    for (int i = tid; i < 128*64; i += 256){
      int jj = i >> 6, kk = i & 63;
      w1c[jj][kk] = W1[(size_t)jj*256 + c*64 + kk];
    }
    __syncthreads();
#pragma unroll 4
    for (int k = 0; k < 64; ++k){
      float wv = w1c[j][k];
#pragma unroll
      for (int r = 0; r < 8; ++r) accv[r] = fmaf(qe[rh*8 + r][c*64 + k], wv, accv[r]);
    }
  }
#pragma unroll
  for (int r = 0; r < 8; ++r) oqa[(size_t)(bt0 + rh*8 + r)*128 + j] = accv[r];
  if (blockIdx.x == 0 && tid < 32) pred[tid * T_] = 0.f;
}

// ---------------- l23: precompute learning part of W2/W3 GEMVs -------------------
// LI[b,t,j] = u32( bf16(b2[j] + W2[j,:256]@[qa[t-1]|qa[t]]) ,
//                  bf16(b3[j] + W3[j,:256]@[qa[t-1]|qa[t]]) )   (qa[-1]=0)
// 128 blocks: (b, t-quarter). Each block: M=32 t-rows, N=128, K=256 bf16 MFMA.
__global__ __launch_bounds__(512) void l23_k(
    const float* __restrict__ oqa,
    const unsigned short* __restrict__ W2b, const unsigned short* __restrict__ W3b,
    const float* __restrict__ b2, const float* __restrict__ b3,
    unsigned short* __restrict__ LIb)
{
  __shared__ unsigned short qab[33*136];    // rows t0-1 .. t0+31 of qa (row 0 may be zeros)
  const int blk = blockIdx.x;
  const int b = blk >> 2, t0 = (blk & 3) * 32;
  const int tid = threadIdx.x;
  const int w = tid >> 6, lane = tid & 63, g = lane >> 4, li = lane & 15;
  const int mt = w & 1, ng = w >> 1;        // m-tile (0..1), n-group (0..3)

  for (int i = tid; i < 33*128; i += 512){
    int row = i >> 7, k = i & 127;
    int tt = t0 - 1 + row;
    qab[row*136 + k] = (tt >= 0) ? f2b(oqa[((size_t)b*T_ + tt)*128 + k]) : (unsigned short)0;
  }
  __syncthreads();

  bf16x8 afr[8];
  {
    int row = mt*16 + li;
#pragma unroll
    for (int ks = 0; ks < 4; ++ks){
      afr[ks]   = *(const bf16x8*)&qab[ row   *136 + ks*32 + 8*g];  // qa[t-1]
      afr[ks+4] = *(const bf16x8*)&qab[(row+1)*136 + ks*32 + 8*g];  // qa[t]
    }
  }
  const int nt[2] = { ng, ng + 4 };
  float o2r[2][4];
#pragma unroll
  for (int m_ = 0; m_ < 2; ++m_){
    const unsigned short* Wp = m_ ? W3b : W2b;
    const float*          bp = m_ ? b3  : b2;
    f32x4 acc[2] = {{0,0,0,0},{0,0,0,0}};
#pragma unroll
    for (int u = 0; u < 2; ++u){
      int j = nt[u]*16 + li;
      const unsigned short* wr = Wp + (size_t)j*384;
#pragma unroll
      for (int ks = 0; ks < 8; ++ks){
        bf16x8 bb = *(const bf16x8*)(wr + ks*32 + 8*g);
        acc[u] = __builtin_amdgcn_mfma_f32_16x16x32_bf16(afr[ks], bb, acc[u], 0,0,0);
      }
    }
#pragma unroll
    for (int u = 0; u < 2; ++u){
      float bias = bp[nt[u]*16 + li];
      if (m_ == 0){
#pragma unroll
        for (int r = 0; r < 4; ++r) o2r[u][r] = acc[u][r] + bias;
      } else {
#pragma unroll
        for (int r = 0; r < 4; ++r){
          int t = t0 + mt*16 + g*4 + r;      // C/D: row=(lane>>4)*4+r, col=lane&15
          int j = nt[u]*16 + li;
          if (t < 127){
            unsigned int p;
            float l3f = acc[u][r] + bias;
            asm("v_cvt_pk_bf16_f32 %0, %1, %2" : "=v"(p) : "v"(o2r[u][r]), "v"(l3f));
            *(unsigned int*)&LIb[(((size_t)b*127 + t)*128 + j)*2] = p;
          }
        }
      }
    }
  }
}

// ---------------- recur: 127-step recurrence, one block per batch -----------------
struct __align__(16) SmR {
  unsigned short hb[2][64*HBS]; // bf16 h, double-buffered (MFMA A operand)
  float qe[3][64];              // qm rows, triple-buffered
  unsigned short htb[128];      // h_tilde bf16 (GEMV A operand, broadcast)
  unsigned short kcb[128];      // KC bf16 (GEMM A operand, broadcast)
  int qdl[T_];
};

__global__ __launch_bounds__(512) void recur_k(
    const int* __restrict__ qd, const float* __restrict__ qmx,
    const float* __restrict__ h0, const float* __restrict__ b4,
    const unsigned short* __restrict__ W2b, const unsigned short* __restrict__ W3b,
    const unsigned short* __restrict__ W4b,
    const unsigned short* __restrict__ LIb,
    float* __restrict__ H, unsigned short* __restrict__ HTg)
{
  __shared__ SmR s;
  const int b   = blockIdx.x;
  const int tid = threadIdx.x;
  const int w = tid >> 6, lane = tid & 63, g = lane >> 4, li = lane & 15;
  const int j = w*16 + li;

  // ---- register-resident weights
  bf16x8 w2cf[4], w3cf[4];      // W2/W3[:, 256:384] rows j (h_tilde slice)
#pragma unroll
  for (int ks = 0; ks < 4; ++ks){
    w2cf[ks] = *(const bf16x8*)(W2b + (size_t)j*384 + 256 + ks*32 + 8*g);
    w3cf[ks] = *(const bf16x8*)(W3b + (size_t)j*384 + 256 + ks*32 + 8*g);
  }
  bf16x8 w4f[8];                // W4 rows j, K=256
#pragma unroll
  for (int ks = 0; ks < 8; ++ks)
    w4f[ks] = *(const bf16x8*)(W4b + (size_t)j*256 + ks*32 + 8*g);
  const float b4v = b4[j];

  // ---- fp32 h state in registers: hreg[mt][r] = h(mt*16+g*4+r, j)
  float hreg[4][4];
#pragma unroll
  for (int mt = 0; mt < 4; ++mt)
#pragma unroll
    for (int r = 0; r < 4; ++r)
      hreg[mt][r] = h0[(mt*16 + g*4 + r)*128 + j];

  // ---- init
  for (int i = tid; i < 64*128; i += 512){
    int n = i >> 7, d = i & 127;
    float v = h0[i];
    s.hb[0][n*HBS + d] = f2b(v);
    H[(size_t)b*8192 + i] = sigf(v);   // H[0] slice, fp32 directly
  }
  if (tid < T_) s.qdl[tid] = qd[b*T_ + tid];
  __syncthreads();
  if (tid < 64){
    s.qe[0][tid] = qmx[(size_t)s.qdl[0]*64 + tid];
    s.qe[1][tid] = qmx[(size_t)s.qdl[1]*64 + tid];
  }
  __syncthreads();
  if (tid < 128){   // h_tilde0
    float acc = 0.f;
    for (int n = 0; n < 64; ++n) acc = fmaf(s.qe[0][n], h0[n*128 + tid], acc);
    s.htb[tid] = f2b(acc);
  }
  __syncthreads();

  unsigned int lv = *(const unsigned int*)&LIb[(((size_t)b*127)*128 + j)*2];
  float l2v = b2f((unsigned short)lv), l3v = b2f((unsigned short)(lv >> 16));
  f32x4 qc4[4];
#pragma unroll
  for (int mt = 0; mt < 4; ++mt) qc4[mt] = *(const f32x4*)&s.qe[0][mt*16 + g*4];

#pragma unroll 1
  for (int t = 0; t < T_-1; ++t){
    const int cur = t & 1, nxt = cur ^ 1;

    // ================= AB phase =================
    int tp1 = (t+1 < 127) ? t+1 : 126;
    unsigned int ln = *(const unsigned int*)&LIb[(((size_t)b*127 + tp1)*128 + j)*2];
    float qmxv = 0.f;
    if (tid < 64 && t+2 < T_) qmxv = qmx[(size_t)s.qdl[t+2]*64 + tid];

    // kc GEMV: 8 independent MFMAs (chain length 1)
    bf16x8 av[4];
#pragma unroll
    for (int ks = 0; ks < 4; ++ks) av[ks] = *(const bf16x8*)&s.htb[ks*32 + 8*g];
    f32x4 q2[4], q3[4];
#pragma unroll
    for (int ks = 0; ks < 4; ++ks){
      f32x4 z = {0,0,0,0};
      q2[ks] = __builtin_amdgcn_mfma_f32_16x16x32_bf16(av[ks], w2cf[ks], z, 0,0,0);
      q3[ks] = __builtin_amdgcn_mfma_f32_16x16x32_bf16(av[ks], w3cf[ks], z, 0,0,0);
    }
    // kc = sigmoid(o3) * sigmoid(2*o2)  [= sig(o3)*(tanh(o2)+1)/2], single rcp
    float o2 = (q2[0][0]+q2[1][0]) + (q2[2][0]+q2[3][0]) + l2v;
    float o3 = (q3[0][0]+q3[1][0]) + (q3[2][0]+q3[3][0]) + l3v;
    float kc = __builtin_amdgcn_rcpf((1.f + __expf(-o3)) * (1.f + __expf(-2.f*o2)));
    if (g == 0) s.kcb[j] = f2b(kc);

    // h-part GEMM (throughput work, 16 MFMAs)
    bf16x8 af[4][4];
#pragma unroll
    for (int mt = 0; mt < 4; ++mt)
#pragma unroll
      for (int ks = 0; ks < 4; ++ks)
        af[mt][ks] = *(const bf16x8*)&s.hb[cur][(mt*16 + li)*HBS + ks*32 + 8*g];
    f32x4 acc[4] = {{0,0,0,0},{0,0,0,0},{0,0,0,0},{0,0,0,0}};
#pragma unroll
    for (int ks = 0; ks < 4; ++ks)
#pragma unroll
      for (int mt = 0; mt < 4; ++mt)
        acc[mt] = __builtin_amdgcn_mfma_f32_16x16x32_bf16(af[mt][ks], w4f[ks], acc[mt], 0,0,0);

    // qn for epilogue
    f32x4 qn4[4];
#pragma unroll
    for (int mt = 0; mt < 4; ++mt)
      qn4[mt] = *(const f32x4*)&s.qe[(t+1)%3][mt*16 + g*4];
    bar_lds();                              // B1: kcb visible

    // ================= C phase =================
    bf16x8 kf[4];
#pragma unroll
    for (int ks = 0; ks < 4; ++ks) kf[ks] = *(const bf16x8*)&s.kcb[ks*32 + 8*g];
    f32x4 zk[4];
#pragma unroll
    for (int ks = 0; ks < 4; ++ks){
      f32x4 z = {0,0,0,0};
      zk[ks] = __builtin_amdgcn_mfma_f32_16x16x32_bf16(kf[ks], w4f[ks+4], z, 0,0,0);
    }
    float ack = (zk[0][0]+zk[1][0]) + (zk[2][0]+zk[3][0]);

    // coalesced RAW bf16 export of h(t) (reads hb[cur]; independent of epilogue)
    if (t >= 1){
      unsigned short* Hu = (unsigned short*)(H + ((size_t)t*B_ + b)*8192);
#pragma unroll
      for (int k = 0; k < 2; ++k){
        int c = tid + k*512;                  // ushort8 chunk in [0,1024)
        int n = c >> 4, o = (c & 15)*8;
        u16x8 hv = *(const u16x8*)&s.hb[cur][n*HBS + o];
        *(u16x8*)&Hu[c*8] = hv;
      }
    }

    float part[4];
#pragma unroll
    for (int mt = 0; mt < 4; ++mt){
      float hn[4], pp = 0.f;
#pragma unroll
      for (int r = 0; r < 4; ++r){
        float sg = sigf(acc[mt][r] + ack + b4v);
        float v = fmaf(qc4[mt][r], kc, sg*hreg[mt][r]);
        hreg[mt][r] = v; hn[r] = v;
        pp = fmaf(qn4[mt][r], v, pp);
      }
      part[mt] = pp;
      unsigned int p01, p23;
      asm("v_cvt_pk_bf16_f32 %0, %1, %2" : "=v"(p01) : "v"(hn[0]), "v"(hn[1]));
      asm("v_cvt_pk_bf16_f32 %0, %1, %2" : "=v"(p23) : "v"(hn[2]), "v"(hn[3]));
      int n0 = mt*16 + g*4;                  // C/D: row=(lane>>4)*4+r, col=lane&15
      unsigned short* bp_ = &s.hb[nxt][n0*HBS + j];
      bp_[0]       = (unsigned short)p01;
      bp_[HBS]     = (unsigned short)(p01 >> 16);
      bp_[2*HBS]   = (unsigned short)p23;
      bp_[3*HBS]   = (unsigned short)(p23 >> 16);
    }
    float prt = (part[0]+part[1]) + (part[2]+part[3]);
    prt += __shfl_xor(prt, 16);
    prt += __shfl_xor(prt, 32);
    if (g == 0){
      unsigned short hb16 = f2b(prt);
      s.htb[j] = hb16;
      HTg[((size_t)b*T_ + t + 1)*128 + j] = hb16;
    }
    if (tid < 64 && t+2 < T_) s.qe[(t+2)%3][tid] = qmxv;
    lv = ln;
    l2v = b2f((unsigned short)lv); l3v = b2f((unsigned short)(lv >> 16));
#pragma unroll
    for (int mt = 0; mt < 4; ++mt) qc4[mt] = qn4[mt];
    bar_lds();                              // B2: htb/hb[nxt]/qe visible
  }
}

// ---------------- post: ypost (blocks 0..126) + hexp (blocks 127..4158) ----------
__global__ __launch_bounds__(256) void post_k(
    const float* __restrict__ oqe, const unsigned short* __restrict__ HT,
    const float* __restrict__ W5, const float* __restrict__ b5,
    float* __restrict__ pred, float* __restrict__ H)
{
  __shared__ float X[32][256];
  __shared__ float w5c[128][33];
  const int tid = threadIdx.x;

  if ((int)blockIdx.x >= 127){
    // ---- hexp role: in-place bf16 -> sigmoid(f32) expansion of one H slice
    const int tb = blockIdx.x - 127;
    const int t  = (tb >> 5) + 1, b = tb & 31;
    float* Hs = H + ((size_t)t*B_ + b)*8192;
    const unsigned short* Hu = (const unsigned short*)Hs;
    u16x8 v[4];
#pragma unroll
    for (int k = 0; k < 4; ++k) v[k] = *(const u16x8*)&Hu[(k*256 + tid)*8];
    __syncthreads();
#pragma unroll
    for (int k = 0; k < 4; ++k){
      int c = k*256 + tid;
      f32x4 lo, hi;
      lo[0]=sigf(b2f(v[k][0])); lo[1]=sigf(b2f(v[k][1]));
      lo[2]=sigf(b2f(v[k][2])); lo[3]=sigf(b2f(v[k][3]));
      hi[0]=sigf(b2f(v[k][4])); hi[1]=sigf(b2f(v[k][5]));
      hi[2]=sigf(b2f(v[k][6])); hi[3]=sigf(b2f(v[k][7]));
      *(f32x4*)&Hs[c*8]     = lo;
      *(f32x4*)&Hs[c*8 + 4] = hi;
    }
    return;
  }

  // ---- ypost role: y GEMV over all b for tau = blockIdx.x + 1
  const int tau = blockIdx.x + 1;
  for (int i = tid; i < 32*128; i += 256){
    int bb = i >> 7, k = i & 127;
    X[bb][k] = oqe[((size_t)bb*T_ + tau)*128 + k];
    X[bb][128 + k] = b2f(HT[((size_t)bb*T_ + tau)*128 + k]);
  }
  const int j = tid & 127, rh = tid >> 7;
  float acc[16];
  float base = b5[j];
#pragma unroll
  for (int r = 0; r < 16; ++r) acc[r] = base;
  for (int c = 0; c < 8; ++c){
    __syncthreads();
    for (int i = tid; i < 128*32; i += 256){
      int jj = i >> 5, kk = i & 31;
      w5c[jj][kk] = W5[(size_t)jj*256 + c*32 + kk];
    }
    __syncthreads();
#pragma unroll 8
    for (int k = 0; k < 32; ++k){
      float wv = w5c[j][k];
#pragma unroll
      for (int r = 0; r < 16; ++r) acc[r] = fmaf(X[rh*16 + r][c*32 + k], wv, acc[r]);
    }
  }
  __syncthreads();
#pragma unroll
  for (int r = 0; r < 16; ++r) X[rh*16 + r][j] = sigf(acc[r]);
  __syncthreads();
  if (tid < 32){
    float ssum = 0.f;
    for (int k = 0; k < 128; ++k) ssum += X[tid][k];
    pred[tid*T_ + tau] = ssum * (1.f/128.f);
  }
}

extern "C" void kernel_launch(void* const* d_in, const int* in_sizes, int n_in,
                              void* d_out, int out_size, void* d_ws, size_t ws_size,
                              hipStream_t stream)
{
  const int*   qd  = (const int*)  d_in[0];
  const float* ad  = (const float*)d_in[1];
  const float* qmx = (const float*)d_in[2];
  const float* qew = (const float*)d_in[3];
  const float* W1  = (const float*)d_in[4];
  const float* b1  = (const float*)d_in[5];
  const float* W2  = (const float*)d_in[6];
  const float* b2  = (const float*)d_in[7];
  const float* W3  = (const float*)d_in[8];
  const float* b3  = (const float*)d_in[9];
  const float* W4  = (const float*)d_in[10];
  const float* b4  = (const float*)d_in[11];
  const float* W5  = (const float*)d_in[12];
  const float* b5  = (const float*)d_in[13];
  const float* h0  = (const float*)d_in[14];

  float* H    = (float*)d_out;                         // [127][32][64][128]
  float* pred = H    + (size_t)127*32*64*128;          // [32][128]
  float* oqe  = pred + (size_t)32*128;                 // [32][128][128]
  float* oqa  = oqe  + (size_t)32*128*128;             // [32][128][128]

  unsigned short* W2b = (unsigned short*)d_ws;         // [128][384] bf16
  unsigned short* W3b = W2b + 128*384;                 // [128][384] bf16
  unsigned short* W4b = W3b + 128*384;                 // [128][256] bf16
  unsigned short* HTg = W4b + 128*256;                 // [32][128][128] bf16 h_tilde
  unsigned short* LIb = HTg + (size_t)32*128*128;      // [32][127][128][2] bf16 (l2,l3)
  float*          S   = (float*)(LIb + (size_t)32*127*128*2);  // [128]

  stage_k<<<192, 256, 0, stream>>>(W2, W3, W4, W1, W2b, W3b, W4b, S);
  prep_k <<<256, 256, 0, stream>>>(qd, ad, qew, W1, b1, S, oqe, oqa, pred);
  l23_k  <<<128, 512, 0, stream>>>(oqa, W2b, W3b, b2, b3, LIb);
  recur_k<<<32,  512, 0, stream>>>(qd, qmx, h0, b4, W2b, W3b, W4b,
                                   LIb, H, HTg);
  post_k <<<127 + 126*32, 256, 0, stream>>>(oqe, HTg, W5, b5, pred, H);
}